// Round 1
// baseline (549.863 us; speedup 1.0000x reference)
//
#include <hip/hip_runtime.h>

#define EPS_BN 1e-5f

typedef __bf16 bf16x8 __attribute__((ext_vector_type(8)));
typedef float f32x4 __attribute__((ext_vector_type(4)));

__device__ __forceinline__ unsigned short f2bf(float f) {
  union { float f; unsigned u; } v; v.f = f;
  unsigned r = v.u + 0x7fffu + ((v.u >> 16) & 1u);
  return (unsigned short)(r >> 16);
}
__device__ __forceinline__ float bf2f(unsigned short h) {
  union { unsigned u; float f; } v; v.u = ((unsigned)h) << 16;
  return v.f;
}

// ---------------- weight prep ----------------
__global__ void cvt_bf16(const float* __restrict__ in, unsigned short* __restrict__ out, int n) {
  int i = blockIdx.x * 256 + threadIdx.x;
  if (i < n) out[i] = f2bf(in[i]);
}

// w2 (256,256,3,3) [o][c][kk] -> w2r [o][kk*256+c]  (bf16)
__global__ void reorder_w2(const float* __restrict__ w2, unsigned short* __restrict__ w2r) {
  int i = blockIdx.x * 256 + threadIdx.x; // < 256*2304
  int o = i / 2304, r = i % 2304;
  int kk = r / 256, c = r % 256;
  w2r[i] = f2bf(w2[(size_t)o * 2304 + c * 9 + kk]);
}

// ---------------- x transpose: (B,1024,4096) f32 -> (B*4096, 1024) bf16 ----------------
__global__ __launch_bounds__(256) void transpose_x(const float* __restrict__ x,
                                                   unsigned short* __restrict__ xT) {
  __shared__ float t[32][33];
  int b = blockIdx.z;
  int p0 = blockIdx.x * 32, c0 = blockIdx.y * 32;
  int tx = threadIdx.x & 31, ty = threadIdx.x >> 5;
  const float* xb = x + (size_t)b * 1024 * 4096;
#pragma unroll
  for (int j = 0; j < 4; ++j) {
    int c = c0 + ty + j * 8;
    t[ty + j * 8][tx] = xb[(size_t)c * 4096 + p0 + tx];
  }
  __syncthreads();
  unsigned short* xTb = xT + (size_t)b * 4096 * 1024;
#pragma unroll
  for (int j = 0; j < 4; ++j) {
    int p = p0 + ty + j * 8;
    xTb[(size_t)p * 1024 + c0 + tx] = f2bf(t[tx][ty + j * 8]);
  }
}

// ---------------- MFMA GEMM: C[M,N] = A[M,K] * Bm[N,K]^T,  bf16 in / f32 acc ----------------
// EPI 1: v=relu(bn1(v)) -> bf16 out, channel = col (N)
// EPI 2: v=relu(bn2(v+bias[col])) -> bf16 out, channel = col
// EPI 3: v=relu(bn3(v)+resid)    -> f32 out, channel = row (M)
template <int EPI>
__global__ __launch_bounds__(256) void gemm_bt(
    const unsigned short* __restrict__ A, const unsigned short* __restrict__ Bm,
    void* __restrict__ outp, const float* __restrict__ gamma, const float* __restrict__ beta,
    const float* __restrict__ mean, const float* __restrict__ var,
    const float* __restrict__ bias, const float* __restrict__ resid,
    int M, int N, int K, long bStrideB, long bStrideOut) {
  __shared__ unsigned short sA[128 * 32];
  __shared__ unsigned short sB[128 * 32];
  int tid = threadIdx.x, lane = tid & 63, wv = tid >> 6;
  int z = blockIdx.z;
  const unsigned short* Bz = Bm + (size_t)z * bStrideB;
  int m0 = blockIdx.y * 128, n0 = blockIdx.x * 128;
  f32x4 acc[4][4] = {};
  int rowA = tid >> 2;          // 0..63
  int kcol = (tid & 3) * 8;     // element offset in K
  int wm = wv & 1, wn = wv >> 1;
  int lane15 = lane & 15, quad8 = (lane >> 4) * 8;

  for (int k0 = 0; k0 < K; k0 += 32) {
    __syncthreads();
#pragma unroll
    for (int r = 0; r < 2; ++r) {
      const unsigned short* gp = A + (size_t)(m0 + r * 64 + rowA) * K + k0 + kcol;
      __builtin_amdgcn_global_load_lds((const __attribute__((address_space(1))) void*)gp,
                                       (__attribute__((address_space(3))) void*)&sA[r * 2048 + wv * 512],
                                       16, 0, 0);
    }
#pragma unroll
    for (int r = 0; r < 2; ++r) {
      const unsigned short* gp = Bz + (size_t)(n0 + r * 64 + rowA) * K + k0 + kcol;
      __builtin_amdgcn_global_load_lds((const __attribute__((address_space(1))) void*)gp,
                                       (__attribute__((address_space(3))) void*)&sB[r * 2048 + wv * 512],
                                       16, 0, 0);
    }
    __syncthreads();
    bf16x8 afr[4], bfr[4];
#pragma unroll
    for (int mi = 0; mi < 4; ++mi)
      afr[mi] = *(const bf16x8*)&sA[(wm * 64 + mi * 16 + lane15) * 32 + quad8];
#pragma unroll
    for (int ni = 0; ni < 4; ++ni)
      bfr[ni] = *(const bf16x8*)&sB[(wn * 64 + ni * 16 + lane15) * 32 + quad8];
#pragma unroll
    for (int mi = 0; mi < 4; ++mi)
#pragma unroll
      for (int ni = 0; ni < 4; ++ni)
        acc[mi][ni] = __builtin_amdgcn_mfma_f32_16x16x32_bf16(afr[mi], bfr[ni], acc[mi][ni], 0, 0, 0);
  }

  // epilogue: D[row][col], row=(lane>>4)*4+reg, col=lane&15 per 16x16 tile
  if constexpr (EPI == 3) {
    float* outF = (float*)outp + (size_t)z * bStrideOut;
    const float* res = resid + (size_t)z * bStrideOut;
#pragma unroll
    for (int mi = 0; mi < 4; ++mi) {
#pragma unroll
      for (int ni = 0; ni < 4; ++ni) {
        int col = n0 + wn * 64 + ni * 16 + lane15;
#pragma unroll
        for (int reg = 0; reg < 4; ++reg) {
          int row = m0 + wm * 64 + mi * 16 + (lane >> 4) * 4 + reg;
          int ch = row;
          float inv = rsqrtf(var[ch] + EPS_BN) * gamma[ch];
          float v = (acc[mi][ni][reg] - mean[ch]) * inv + beta[ch];
          v += res[(size_t)row * N + col];
          outF[(size_t)row * N + col] = fmaxf(v, 0.f);
        }
      }
    }
  } else {
    unsigned short* outH = (unsigned short*)outp;
#pragma unroll
    for (int mi = 0; mi < 4; ++mi) {
#pragma unroll
      for (int ni = 0; ni < 4; ++ni) {
        int col = n0 + wn * 64 + ni * 16 + lane15;
        int ch = col;
        float inv = rsqrtf(var[ch] + EPS_BN) * gamma[ch];
        float mu = mean[ch], bt = beta[ch];
        float bi = (EPI == 2) ? bias[ch] : 0.f;
#pragma unroll
        for (int reg = 0; reg < 4; ++reg) {
          int row = m0 + wm * 64 + mi * 16 + (lane >> 4) * 4 + reg;
          float v = acc[mi][ni][reg] + bi;
          v = (v - mu) * inv + bt;
          outH[(size_t)row * N + col] = f2bf(fmaxf(v, 0.f));
        }
      }
    }
  }
}

// ---------------- offset conv: 18ch dilated 3x3 direct conv over act1T (P,C bf16) ----------------
__global__ __launch_bounds__(256) void off_conv(const unsigned short* __restrict__ act1T,
                                                const float* __restrict__ woff,
                                                const float* __restrict__ boff,
                                                float* __restrict__ offs) {
  int w = threadIdx.x & 63;
  int h = blockIdx.x * 4 + (threadIdx.x >> 6);
  int o = blockIdx.y, b = blockIdx.z;
  float acc = 0.f;
  const unsigned short* actb = act1T + (size_t)b * 4096 * 256;
  for (int kk = 0; kk < 9; ++kk) {
    int y = h + (kk / 3) * 2 - 2;
    int x = w + (kk % 3) * 2 - 2;
    if (y < 0 || y >= 64 || x < 0 || x >= 64) continue;
    const unsigned short* base = actb + ((size_t)(y * 64 + x)) * 256;
    const float* wf = woff + (size_t)o * 2304 + kk;
    for (int c = 0; c < 256; c += 8) {
      uint4 pk = *(const uint4*)(base + c);
      unsigned u[4] = {pk.x, pk.y, pk.z, pk.w};
#pragma unroll
      for (int j = 0; j < 4; ++j) {
        float lo = bf2f((unsigned short)(u[j] & 0xffffu));
        float hi = bf2f((unsigned short)(u[j] >> 16));
        acc += lo * wf[(c + 2 * j) * 9] + hi * wf[(c + 2 * j + 1) * 9];
      }
    }
  }
  offs[((size_t)(b * 18 + o)) * 4096 + h * 64 + w] = acc + boff[o];
}

// ---------------- bilinear im2col: S[b*4096+p][kk*256+c] bf16 ----------------
__global__ __launch_bounds__(256) void deform_sample(const unsigned short* __restrict__ act1T,
                                                     const float* __restrict__ offs,
                                                     unsigned short* __restrict__ S) {
  int p = blockIdx.x, b = blockIdx.y, c = threadIdx.x;
  int h = p >> 6, w = p & 63;
  const unsigned short* actb = act1T + (size_t)b * 4096 * 256;
  unsigned short* Sp = S + ((size_t)(b * 4096 + p)) * 2304;
  const float* ob = offs + (size_t)b * 18 * 4096;
#pragma unroll
  for (int kk = 0; kk < 9; ++kk) {
    float offy = ob[(size_t)(2 * kk) * 4096 + p];
    float offx = ob[(size_t)(2 * kk + 1) * 4096 + p];
    float py = (float)(h + (kk / 3) * 2 - 2) + offy;
    float px = (float)(w + (kk % 3) * 2 - 2) + offx;
    float fy = floorf(py), fx = floorf(px);
    int y0 = (int)fy, x0 = (int)fx;
    float wy = py - fy, wx = px - fx;
    float v00 = 0.f, v01 = 0.f, v10 = 0.f, v11 = 0.f;
    bool yv0 = (y0 >= 0 && y0 < 64), yv1 = (y0 + 1 >= 0 && y0 + 1 < 64);
    bool xv0 = (x0 >= 0 && x0 < 64), xv1 = (x0 + 1 >= 0 && x0 + 1 < 64);
    if (yv0 && xv0) v00 = bf2f(actb[((size_t)(y0 * 64 + x0)) * 256 + c]);
    if (yv0 && xv1) v01 = bf2f(actb[((size_t)(y0 * 64 + x0 + 1)) * 256 + c]);
    if (yv1 && xv0) v10 = bf2f(actb[((size_t)((y0 + 1) * 64 + x0)) * 256 + c]);
    if (yv1 && xv1) v11 = bf2f(actb[((size_t)((y0 + 1) * 64 + x0 + 1)) * 256 + c]);
    float val = v00 * (1.f - wy) * (1.f - wx) + v01 * (1.f - wy) * wx +
                v10 * wy * (1.f - wx) + v11 * wy * wx;
    Sp[kk * 256 + c] = f2bf(val);
  }
}

extern "C" void kernel_launch(void* const* d_in, const int* in_sizes, int n_in,
                              void* d_out, int out_size, void* d_ws, size_t ws_size,
                              hipStream_t stream) {
  const float* x      = (const float*)d_in[0];
  const float* w1     = (const float*)d_in[1];
  const float* gamma1 = (const float*)d_in[2];
  const float* beta1  = (const float*)d_in[3];
  const float* mean1  = (const float*)d_in[4];
  const float* var1   = (const float*)d_in[5];
  const float* woff   = (const float*)d_in[6];
  const float* boff   = (const float*)d_in[7];
  const float* w2     = (const float*)d_in[8];
  const float* bconv2 = (const float*)d_in[9];
  const float* gamma2 = (const float*)d_in[10];
  const float* beta2  = (const float*)d_in[11];
  const float* mean2  = (const float*)d_in[12];
  const float* var2   = (const float*)d_in[13];
  const float* w3     = (const float*)d_in[14];
  const float* gamma3 = (const float*)d_in[15];
  const float* beta3  = (const float*)d_in[16];
  const float* mean3  = (const float*)d_in[17];
  const float* var3   = (const float*)d_in[18];

  char* ws = (char*)d_ws;
  unsigned short* xT    = (unsigned short*)(ws);                 // 33,554,432 B
  unsigned short* act1T = (unsigned short*)(ws + 33554432);      //  8,388,608
  unsigned short* act2T = (unsigned short*)(ws + 41943040);      //  8,388,608
  unsigned short* S     = (unsigned short*)(ws + 50331648);      // 75,497,472
  float*          offs  = (float*)(ws + 125829120);              //  1,179,648
  unsigned short* w1b   = (unsigned short*)(ws + 127008768);     //    524,288
  unsigned short* w2r   = (unsigned short*)(ws + 127533056);     //  1,179,648
  unsigned short* w3b   = (unsigned short*)(ws + 128712704);     //    524,288

  cvt_bf16<<<1024, 256, 0, stream>>>(w1, w1b, 262144);
  cvt_bf16<<<1024, 256, 0, stream>>>(w3, w3b, 262144);
  reorder_w2<<<2304, 256, 0, stream>>>(w2, w2r);
  transpose_x<<<dim3(128, 32, 4), 256, 0, stream>>>(x, xT);

  // act1T[p][o] = relu(bn1(x @ w1^T))
  gemm_bt<1><<<dim3(2, 128, 1), 256, 0, stream>>>(xT, w1b, act1T, gamma1, beta1, mean1, var1,
                                                  nullptr, nullptr, 16384, 256, 1024, 0, 0);
  off_conv<<<dim3(16, 18, 4), 256, 0, stream>>>(act1T, woff, boff, offs);
  deform_sample<<<dim3(4096, 4), 256, 0, stream>>>(act1T, offs, S);
  // act2T[p][o] = relu(bn2(S @ w2r^T + bconv2))
  gemm_bt<2><<<dim3(2, 128, 1), 256, 0, stream>>>(S, w2r, act2T, gamma2, beta2, mean2, var2,
                                                  bconv2, nullptr, 16384, 256, 2304, 0, 0);
  // out[b][o][p] = relu(bn3(w3 @ act2T^T) + x)
  gemm_bt<3><<<dim3(32, 8, 4), 256, 0, stream>>>(w3b, act2T, d_out, gamma3, beta3, mean3, var3,
                                                 nullptr, x, 1024, 4096, 256, 4096L * 256,
                                                 4194304L);
}

// Round 2
// 395.780 us; speedup vs baseline: 1.3893x; 1.3893x over previous
//
#include <hip/hip_runtime.h>

#define EPS_BN 1e-5f

typedef __bf16 bf16x8 __attribute__((ext_vector_type(8)));
typedef float f32x4 __attribute__((ext_vector_type(4)));

__device__ __forceinline__ unsigned short f2bf(float f) {
  union { float f; unsigned u; } v; v.f = f;
  unsigned r = v.u + 0x7fffu + ((v.u >> 16) & 1u);
  return (unsigned short)(r >> 16);
}
__device__ __forceinline__ float bf2f(unsigned short h) {
  union { unsigned u; float f; } v; v.u = ((unsigned)h) << 16;
  return v.f;
}

// ---------------- weight prep ----------------
__global__ void cvt_bf16(const float* __restrict__ in, unsigned short* __restrict__ out, int n) {
  int i = blockIdx.x * 256 + threadIdx.x;
  if (i < n) out[i] = f2bf(in[i]);
}

__global__ void zero16(uint4* __restrict__ p, int n16) {
  int i = blockIdx.x * 256 + threadIdx.x;
  if (i < n16) p[i] = uint4{0, 0, 0, 0};
}

// w2 (256,256,3,3) [o][c][kk] -> w2r [o][kk*256+c]  (bf16)
__global__ void reorder_w2(const float* __restrict__ w2, unsigned short* __restrict__ w2r) {
  int i = blockIdx.x * 256 + threadIdx.x; // < 256*2304
  int o = i / 2304, r = i % 2304;
  int kk = r / 256, c = r % 256;
  w2r[i] = f2bf(w2[(size_t)o * 2304 + c * 9 + kk]);
}

// woff (18,256,3,3) -> wob [32][kk*256+c] bf16, rows 18..31 zero
__global__ void reorder_woff(const float* __restrict__ woff, unsigned short* __restrict__ wob) {
  int i = blockIdx.x * 256 + threadIdx.x; // < 32*2304
  if (i >= 32 * 2304) return;
  int o = i / 2304, r = i % 2304;
  int kk = r / 256, c = r % 256;
  wob[i] = (o < 18) ? f2bf(woff[(size_t)o * 2304 + c * 9 + kk]) : (unsigned short)0;
}

// ---------------- x transpose: (B,1024,4096) f32 -> (B*4096, 1024) bf16 ----------------
__global__ __launch_bounds__(256) void transpose_x(const float* __restrict__ x,
                                                   unsigned short* __restrict__ xT) {
  __shared__ float t[32][33];
  int b = blockIdx.z;
  int p0 = blockIdx.x * 32, c0 = blockIdx.y * 32;
  int tx = threadIdx.x & 31, ty = threadIdx.x >> 5;
  const float* xb = x + (size_t)b * 1024 * 4096;
#pragma unroll
  for (int j = 0; j < 4; ++j) {
    int c = c0 + ty + j * 8;
    t[ty + j * 8][tx] = xb[(size_t)c * 4096 + p0 + tx];
  }
  __syncthreads();
  unsigned short* xTb = xT + (size_t)b * 4096 * 1024;
#pragma unroll
  for (int j = 0; j < 4; ++j) {
    int p = p0 + ty + j * 8;
    xTb[(size_t)p * 1024 + c0 + tx] = f2bf(t[tx][ty + j * 8]);
  }
}

// ---------------- MFMA GEMM: C[M,N] = A[M,K] * Bm[N,K]^T,  bf16 in / f32 acc ----------------
// EPI 1: v=relu(bn1(v)) -> bf16 out (pixel-major) AND padded copy (B,68,68,256)
// EPI 2: v=relu(bn2(v+bias[col])) -> bf16 out, channel = col
// EPI 3: v=relu(bn3(v)+resid)    -> f32 out, channel = row (M)
template <int EPI>
__global__ __launch_bounds__(256) void gemm_bt(
    const unsigned short* __restrict__ A, const unsigned short* __restrict__ Bm,
    void* __restrict__ outp, unsigned short* __restrict__ out2,
    const float* __restrict__ gamma, const float* __restrict__ beta,
    const float* __restrict__ mean, const float* __restrict__ var,
    const float* __restrict__ bias, const float* __restrict__ resid,
    int M, int N, int K, long bStrideB, long bStrideOut) {
  __shared__ unsigned short sA[128 * 32];
  __shared__ unsigned short sB[128 * 32];
  int tid = threadIdx.x, lane = tid & 63, wv = tid >> 6;
  int z = blockIdx.z;
  const unsigned short* Bz = Bm + (size_t)z * bStrideB;
  int m0 = blockIdx.y * 128, n0 = blockIdx.x * 128;
  f32x4 acc[4][4] = {};
  int rowA = tid >> 2;          // 0..63
  int kcol = (tid & 3) * 8;     // element offset in K
  int wm = wv & 1, wn = wv >> 1;
  int lane15 = lane & 15, quad8 = (lane >> 4) * 8;

  for (int k0 = 0; k0 < K; k0 += 32) {
    __syncthreads();
#pragma unroll
    for (int r = 0; r < 2; ++r) {
      const unsigned short* gp = A + (size_t)(m0 + r * 64 + rowA) * K + k0 + kcol;
      __builtin_amdgcn_global_load_lds((const __attribute__((address_space(1))) void*)gp,
                                       (__attribute__((address_space(3))) void*)&sA[r * 2048 + wv * 512],
                                       16, 0, 0);
    }
#pragma unroll
    for (int r = 0; r < 2; ++r) {
      const unsigned short* gp = Bz + (size_t)(n0 + r * 64 + rowA) * K + k0 + kcol;
      __builtin_amdgcn_global_load_lds((const __attribute__((address_space(1))) void*)gp,
                                       (__attribute__((address_space(3))) void*)&sB[r * 2048 + wv * 512],
                                       16, 0, 0);
    }
    __syncthreads();
    bf16x8 afr[4], bfr[4];
#pragma unroll
    for (int mi = 0; mi < 4; ++mi)
      afr[mi] = *(const bf16x8*)&sA[(wm * 64 + mi * 16 + lane15) * 32 + quad8];
#pragma unroll
    for (int ni = 0; ni < 4; ++ni)
      bfr[ni] = *(const bf16x8*)&sB[(wn * 64 + ni * 16 + lane15) * 32 + quad8];
#pragma unroll
    for (int mi = 0; mi < 4; ++mi)
#pragma unroll
      for (int ni = 0; ni < 4; ++ni)
        acc[mi][ni] = __builtin_amdgcn_mfma_f32_16x16x32_bf16(afr[mi], bfr[ni], acc[mi][ni], 0, 0, 0);
  }

  // epilogue: D[row][col], row=(lane>>4)*4+reg, col=lane&15 per 16x16 tile
  if constexpr (EPI == 3) {
    float* outF = (float*)outp + (size_t)z * bStrideOut;
    const float* res = resid + (size_t)z * bStrideOut;
#pragma unroll
    for (int mi = 0; mi < 4; ++mi) {
#pragma unroll
      for (int ni = 0; ni < 4; ++ni) {
        int col = n0 + wn * 64 + ni * 16 + lane15;
#pragma unroll
        for (int reg = 0; reg < 4; ++reg) {
          int row = m0 + wm * 64 + mi * 16 + (lane >> 4) * 4 + reg;
          int ch = row;
          float inv = rsqrtf(var[ch] + EPS_BN) * gamma[ch];
          float v = (acc[mi][ni][reg] - mean[ch]) * inv + beta[ch];
          v += res[(size_t)row * N + col];
          outF[(size_t)row * N + col] = fmaxf(v, 0.f);
        }
      }
    }
  } else {
    unsigned short* outH = (unsigned short*)outp;
#pragma unroll
    for (int mi = 0; mi < 4; ++mi) {
#pragma unroll
      for (int ni = 0; ni < 4; ++ni) {
        int col = n0 + wn * 64 + ni * 16 + lane15;
        int ch = col;
        float inv = rsqrtf(var[ch] + EPS_BN) * gamma[ch];
        float mu = mean[ch], bt = beta[ch];
        float bi = (EPI == 2) ? bias[ch] : 0.f;
#pragma unroll
        for (int reg = 0; reg < 4; ++reg) {
          int row = m0 + wm * 64 + mi * 16 + (lane >> 4) * 4 + reg;
          float v = acc[mi][ni][reg] + bi;
          v = (v - mu) * inv + bt;
          unsigned short hv = f2bf(fmaxf(v, 0.f));
          outH[(size_t)row * N + col] = hv;
          if constexpr (EPI == 1) {
            int b = row >> 12, p = row & 4095;
            out2[(((size_t)(b * 68) + (p >> 6) + 2) * 68 + (p & 63) + 2) * 256 + col] = hv;
          }
        }
      }
    }
  }
}

// ---------------- offset conv as MFMA GEMM over padded act1P ----------------
// offs[b][o][p] = sum_kk sum_c act1P[b][h+2+dy][w+2+dx][c] * wob[o][kk*256+c] + boff[o]
__global__ __launch_bounds__(256) void off_gemm(const unsigned short* __restrict__ actP,
                                                const unsigned short* __restrict__ wob,
                                                const float* __restrict__ boff,
                                                float* __restrict__ offs) {
  __shared__ unsigned short sA[64 * 64];  // 64 rows x 64 k
  __shared__ unsigned short sB[32 * 64];  // 32 o   x 64 k
  int tid = threadIdx.x, lane = tid & 63, wv = tid >> 6;
  int m0 = blockIdx.x * 64;
  int lane15 = lane & 15, quad8 = (lane >> 4) * 8;
  int rowA = tid >> 3;            // 0..31
  int kc = (tid & 7) * 8;         // k element offset within BK=64

  // per-thread padded base addresses for the two staged row-groups
  const unsigned short* baseA[2];
#pragma unroll
  for (int r = 0; r < 2; ++r) {
    int row = m0 + r * 32 + rowA;
    int b = row >> 12, p = row & 4095;
    baseA[r] = actP + (((size_t)(b * 68) + (p >> 6) + 2) * 68 + (p & 63) + 2) * 256 + kc;
  }
  const unsigned short* baseB = wob + (size_t)rowA * 2304 + kc;

  f32x4 acc[2] = {};
  for (int kk = 0; kk < 9; ++kk) {
    int shift = ((kk / 3) * 2 - 2) * 68 + ((kk % 3) * 2 - 2);  // pixel shift (padded coords)
#pragma unroll 1
    for (int c0 = 0; c0 < 256; c0 += 64) {
      __syncthreads();
#pragma unroll
      for (int r = 0; r < 2; ++r) {
        const unsigned short* gp = baseA[r] + (long)shift * 256 + c0;
        __builtin_amdgcn_global_load_lds((const __attribute__((address_space(1))) void*)gp,
                                         (__attribute__((address_space(3))) void*)&sA[r * 2048 + wv * 512],
                                         16, 0, 0);
      }
      {
        const unsigned short* gp = baseB + kk * 256 + c0;
        __builtin_amdgcn_global_load_lds((const __attribute__((address_space(1))) void*)gp,
                                         (__attribute__((address_space(3))) void*)&sB[wv * 512],
                                         16, 0, 0);
      }
      __syncthreads();
      bf16x8 afr[2], bfr[2][2];
#pragma unroll
      for (int kq = 0; kq < 2; ++kq) {
        afr[kq] = *(const bf16x8*)&sA[(wv * 16 + lane15) * 64 + kq * 32 + quad8];
#pragma unroll
        for (int ni = 0; ni < 2; ++ni)
          bfr[kq][ni] = *(const bf16x8*)&sB[(ni * 16 + lane15) * 64 + kq * 32 + quad8];
      }
#pragma unroll
      for (int kq = 0; kq < 2; ++kq)
#pragma unroll
        for (int ni = 0; ni < 2; ++ni)
          acc[ni] = __builtin_amdgcn_mfma_f32_16x16x32_bf16(afr[kq], bfr[kq][ni], acc[ni], 0, 0, 0);
    }
  }

  // epilogue: row = m0 + wv*16 + (lane>>4)*4 + reg, col(o) = ni*16 + lane15
#pragma unroll
  for (int ni = 0; ni < 2; ++ni) {
    int o = ni * 16 + lane15;
    if (o < 18) {
      float bo = boff[o];
#pragma unroll
      for (int reg = 0; reg < 4; ++reg) {
        int row = m0 + wv * 16 + (lane >> 4) * 4 + reg;
        int b = row >> 12, p = row & 4095;
        offs[((size_t)(b * 18 + o)) * 4096 + p] = acc[ni][reg] + bo;
      }
    }
  }
}

// ---------------- bilinear im2col: S[b*4096+p][kk*256+c] bf16 ----------------
__global__ __launch_bounds__(256) void deform_sample(const unsigned short* __restrict__ act1T,
                                                     const float* __restrict__ offs,
                                                     unsigned short* __restrict__ S) {
  int p = blockIdx.x, b = blockIdx.y, c = threadIdx.x;
  int h = p >> 6, w = p & 63;
  const unsigned short* actb = act1T + (size_t)b * 4096 * 256;
  unsigned short* Sp = S + ((size_t)(b * 4096 + p)) * 2304;
  const float* ob = offs + (size_t)b * 18 * 4096;
#pragma unroll
  for (int kk = 0; kk < 9; ++kk) {
    float offy = ob[(size_t)(2 * kk) * 4096 + p];
    float offx = ob[(size_t)(2 * kk + 1) * 4096 + p];
    float py = (float)(h + (kk / 3) * 2 - 2) + offy;
    float px = (float)(w + (kk % 3) * 2 - 2) + offx;
    float fy = floorf(py), fx = floorf(px);
    int y0 = (int)fy, x0 = (int)fx;
    float wy = py - fy, wx = px - fx;
    float v00 = 0.f, v01 = 0.f, v10 = 0.f, v11 = 0.f;
    bool yv0 = (y0 >= 0 && y0 < 64), yv1 = (y0 + 1 >= 0 && y0 + 1 < 64);
    bool xv0 = (x0 >= 0 && x0 < 64), xv1 = (x0 + 1 >= 0 && x0 + 1 < 64);
    if (yv0 && xv0) v00 = bf2f(actb[((size_t)(y0 * 64 + x0)) * 256 + c]);
    if (yv0 && xv1) v01 = bf2f(actb[((size_t)(y0 * 64 + x0 + 1)) * 256 + c]);
    if (yv1 && xv0) v10 = bf2f(actb[((size_t)((y0 + 1) * 64 + x0)) * 256 + c]);
    if (yv1 && xv1) v11 = bf2f(actb[((size_t)((y0 + 1) * 64 + x0 + 1)) * 256 + c]);
    float val = v00 * (1.f - wy) * (1.f - wx) + v01 * (1.f - wy) * wx +
                v10 * wy * (1.f - wx) + v11 * wy * wx;
    Sp[kk * 256 + c] = f2bf(val);
  }
}

extern "C" void kernel_launch(void* const* d_in, const int* in_sizes, int n_in,
                              void* d_out, int out_size, void* d_ws, size_t ws_size,
                              hipStream_t stream) {
  const float* x      = (const float*)d_in[0];
  const float* w1     = (const float*)d_in[1];
  const float* gamma1 = (const float*)d_in[2];
  const float* beta1  = (const float*)d_in[3];
  const float* mean1  = (const float*)d_in[4];
  const float* var1   = (const float*)d_in[5];
  const float* woff   = (const float*)d_in[6];
  const float* boff   = (const float*)d_in[7];
  const float* w2     = (const float*)d_in[8];
  const float* bconv2 = (const float*)d_in[9];
  const float* gamma2 = (const float*)d_in[10];
  const float* beta2  = (const float*)d_in[11];
  const float* mean2  = (const float*)d_in[12];
  const float* var2   = (const float*)d_in[13];
  const float* w3     = (const float*)d_in[14];
  const float* gamma3 = (const float*)d_in[15];
  const float* beta3  = (const float*)d_in[16];
  const float* mean3  = (const float*)d_in[17];
  const float* var3   = (const float*)d_in[18];

  char* ws = (char*)d_ws;
  unsigned short* xT    = (unsigned short*)(ws);                 // 33,554,432 B
  unsigned short* act1T = (unsigned short*)(ws + 33554432);      //  8,388,608
  unsigned short* act2T = (unsigned short*)(ws + 41943040);      //  8,388,608
  unsigned short* S     = (unsigned short*)(ws + 50331648);      // 75,497,472
  float*          offs  = (float*)(ws + 125829120);              //  1,179,648
  unsigned short* w1b   = (unsigned short*)(ws + 127008768);     //    524,288
  unsigned short* w2r   = (unsigned short*)(ws + 127533056);     //  1,179,648
  unsigned short* w3b   = (unsigned short*)(ws + 128712704);     //    524,288
  // aliased (non-overlapping lifetimes):
  unsigned short* act1P = S;                  // (B,68,68,256) bf16 = 9,469,952 B; dead before S written
  unsigned short* wob   = xT;                 // 32*2304*2 = 147,456 B; written after gemm1 (xT dead)

  cvt_bf16<<<1024, 256, 0, stream>>>(w1, w1b, 262144);
  cvt_bf16<<<1024, 256, 0, stream>>>(w3, w3b, 262144);
  reorder_w2<<<2304, 256, 0, stream>>>(w2, w2r);
  zero16<<<2312, 256, 0, stream>>>((uint4*)act1P, 591872);   // zero padded act1 (incl. halo)
  transpose_x<<<dim3(128, 32, 4), 256, 0, stream>>>(x, xT);

  // act1T[p][o] = relu(bn1(x @ w1^T));  also writes padded act1P
  gemm_bt<1><<<dim3(2, 128, 1), 256, 0, stream>>>(xT, w1b, act1T, act1P, gamma1, beta1, mean1,
                                                  var1, nullptr, nullptr, 16384, 256, 1024, 0, 0);
  // xT now dead -> build wob in its place
  reorder_woff<<<288, 256, 0, stream>>>(woff, wob);
  off_gemm<<<256, 256, 0, stream>>>(act1P, wob, boff, offs);
  deform_sample<<<dim3(4096, 4), 256, 0, stream>>>(act1T, offs, S);
  // act2T[p][o] = relu(bn2(S @ w2r^T + bconv2))
  gemm_bt<2><<<dim3(2, 128, 1), 256, 0, stream>>>(S, w2r, act2T, nullptr, gamma2, beta2, mean2,
                                                  var2, bconv2, nullptr, 16384, 256, 2304, 0, 0);
  // out[b][o][p] = relu(bn3(w3 @ act2T^T) + x)
  gemm_bt<3><<<dim3(32, 8, 4), 256, 0, stream>>>(w3b, act2T, d_out, nullptr, gamma3, beta3, mean3,
                                                 var3, nullptr, x, 1024, 4096, 256, 4096L * 256,
                                                 4194304L);
}

// Round 3
// 325.898 us; speedup vs baseline: 1.6872x; 1.2144x over previous
//
#include <hip/hip_runtime.h>

#define EPS_BN 1e-5f

typedef __bf16 bf16x8 __attribute__((ext_vector_type(8)));
typedef float f32x4 __attribute__((ext_vector_type(4)));

__device__ __forceinline__ unsigned short f2bf(float f) {
  union { float f; unsigned u; } v; v.f = f;
  unsigned r = v.u + 0x7fffu + ((v.u >> 16) & 1u);
  return (unsigned short)(r >> 16);
}
__device__ __forceinline__ float bf2f(unsigned short h) {
  union { unsigned u; float f; } v; v.u = ((unsigned)h) << 16;
  return v.f;
}

// ---------------- weight prep ----------------
__global__ void cvt_bf16(const float* __restrict__ in, unsigned short* __restrict__ out, int n) {
  int i = blockIdx.x * 256 + threadIdx.x;
  if (i < n) out[i] = f2bf(in[i]);
}

__global__ void zero16(uint4* __restrict__ p, int n16) {
  int i = blockIdx.x * 256 + threadIdx.x;
  if (i < n16) p[i] = uint4{0, 0, 0, 0};
}

// w2 (256,256,3,3) [o][c][kk] -> w2r [o][kk*256+c]  (bf16)
__global__ void reorder_w2(const float* __restrict__ w2, unsigned short* __restrict__ w2r) {
  int i = blockIdx.x * 256 + threadIdx.x; // < 256*2304
  int o = i / 2304, r = i % 2304;
  int kk = r / 256, c = r % 256;
  w2r[i] = f2bf(w2[(size_t)o * 2304 + c * 9 + kk]);
}

// woff (18,256,3,3) -> wob [32][kk*256+c] bf16, rows 18..31 zero
__global__ void reorder_woff(const float* __restrict__ woff, unsigned short* __restrict__ wob) {
  int i = blockIdx.x * 256 + threadIdx.x; // < 32*2304
  if (i >= 32 * 2304) return;
  int o = i / 2304, r = i % 2304;
  int kk = r / 256, c = r % 256;
  wob[i] = (o < 18) ? f2bf(woff[(size_t)o * 2304 + c * 9 + kk]) : (unsigned short)0;
}

// ---------------- x transpose: (B,1024,4096) f32 -> (B*4096, 1024) bf16 ----------------
__global__ __launch_bounds__(256) void transpose_x(const float* __restrict__ x,
                                                   unsigned short* __restrict__ xT) {
  __shared__ float t[32][33];
  int b = blockIdx.z;
  int p0 = blockIdx.x * 32, c0 = blockIdx.y * 32;
  int tx = threadIdx.x & 31, ty = threadIdx.x >> 5;
  const float* xb = x + (size_t)b * 1024 * 4096;
#pragma unroll
  for (int j = 0; j < 4; ++j) {
    int c = c0 + ty + j * 8;
    t[ty + j * 8][tx] = xb[(size_t)c * 4096 + p0 + tx];
  }
  __syncthreads();
  unsigned short* xTb = xT + (size_t)b * 4096 * 1024;
#pragma unroll
  for (int j = 0; j < 4; ++j) {
    int p = p0 + ty + j * 8;
    xTb[(size_t)p * 1024 + c0 + tx] = f2bf(t[tx][ty + j * 8]);
  }
}

// ---------------- MFMA GEMM: C[M,N] = A[M,K] * Bm[N,K]^T,  bf16 in / f32 acc ----------------
template <int EPI>
__global__ __launch_bounds__(256) void gemm_bt(
    const unsigned short* __restrict__ A, const unsigned short* __restrict__ Bm,
    void* __restrict__ outp, unsigned short* __restrict__ out2,
    const float* __restrict__ gamma, const float* __restrict__ beta,
    const float* __restrict__ mean, const float* __restrict__ var,
    const float* __restrict__ bias, const float* __restrict__ resid,
    int M, int N, int K, long bStrideB, long bStrideOut) {
  __shared__ unsigned short sA[128 * 32];
  __shared__ unsigned short sB[128 * 32];
  int tid = threadIdx.x, lane = tid & 63, wv = tid >> 6;
  int z = blockIdx.z;
  const unsigned short* Bz = Bm + (size_t)z * bStrideB;
  int m0 = blockIdx.y * 128, n0 = blockIdx.x * 128;
  f32x4 acc[4][4] = {};
  int rowA = tid >> 2;          // 0..63
  int kcol = (tid & 3) * 8;     // element offset in K
  int wm = wv & 1, wn = wv >> 1;
  int lane15 = lane & 15, quad8 = (lane >> 4) * 8;

  for (int k0 = 0; k0 < K; k0 += 32) {
    __syncthreads();
#pragma unroll
    for (int r = 0; r < 2; ++r) {
      const unsigned short* gp = A + (size_t)(m0 + r * 64 + rowA) * K + k0 + kcol;
      __builtin_amdgcn_global_load_lds((const __attribute__((address_space(1))) void*)gp,
                                       (__attribute__((address_space(3))) void*)&sA[r * 2048 + wv * 512],
                                       16, 0, 0);
    }
#pragma unroll
    for (int r = 0; r < 2; ++r) {
      const unsigned short* gp = Bz + (size_t)(n0 + r * 64 + rowA) * K + k0 + kcol;
      __builtin_amdgcn_global_load_lds((const __attribute__((address_space(1))) void*)gp,
                                       (__attribute__((address_space(3))) void*)&sB[r * 2048 + wv * 512],
                                       16, 0, 0);
    }
    __syncthreads();
    bf16x8 afr[4], bfr[4];
#pragma unroll
    for (int mi = 0; mi < 4; ++mi)
      afr[mi] = *(const bf16x8*)&sA[(wm * 64 + mi * 16 + lane15) * 32 + quad8];
#pragma unroll
    for (int ni = 0; ni < 4; ++ni)
      bfr[ni] = *(const bf16x8*)&sB[(wn * 64 + ni * 16 + lane15) * 32 + quad8];
#pragma unroll
    for (int mi = 0; mi < 4; ++mi)
#pragma unroll
      for (int ni = 0; ni < 4; ++ni)
        acc[mi][ni] = __builtin_amdgcn_mfma_f32_16x16x32_bf16(afr[mi], bfr[ni], acc[mi][ni], 0, 0, 0);
  }

  if constexpr (EPI == 3) {
    float* outF = (float*)outp + (size_t)z * bStrideOut;
    const float* res = resid + (size_t)z * bStrideOut;
#pragma unroll
    for (int mi = 0; mi < 4; ++mi) {
#pragma unroll
      for (int ni = 0; ni < 4; ++ni) {
        int col = n0 + wn * 64 + ni * 16 + lane15;
#pragma unroll
        for (int reg = 0; reg < 4; ++reg) {
          int row = m0 + wm * 64 + mi * 16 + (lane >> 4) * 4 + reg;
          int ch = row;
          float inv = rsqrtf(var[ch] + EPS_BN) * gamma[ch];
          float v = (acc[mi][ni][reg] - mean[ch]) * inv + beta[ch];
          v += res[(size_t)row * N + col];
          outF[(size_t)row * N + col] = fmaxf(v, 0.f);
        }
      }
    }
  } else {
    unsigned short* outH = (unsigned short*)outp;
#pragma unroll
    for (int mi = 0; mi < 4; ++mi) {
#pragma unroll
      for (int ni = 0; ni < 4; ++ni) {
        int col = n0 + wn * 64 + ni * 16 + lane15;
        int ch = col;
        float inv = rsqrtf(var[ch] + EPS_BN) * gamma[ch];
        float mu = mean[ch], bt = beta[ch];
        float bi = (EPI == 2) ? bias[ch] : 0.f;
#pragma unroll
        for (int reg = 0; reg < 4; ++reg) {
          int row = m0 + wm * 64 + mi * 16 + (lane >> 4) * 4 + reg;
          float v = acc[mi][ni][reg] + bi;
          v = (v - mu) * inv + bt;
          unsigned short hv = f2bf(fmaxf(v, 0.f));
          outH[(size_t)row * N + col] = hv;
          if constexpr (EPI == 1) {
            int b = row >> 12, p = row & 4095;
            out2[(((size_t)(b * 68) + (p >> 6) + 2) * 68 + (p & 63) + 2) * 256 + col] = hv;
          }
        }
      }
    }
  }
}

// ---------------- offset conv as MFMA GEMM over padded act1P ----------------
// offsP[(b*4096+p)*18 + o] = sum_kk,c act1P[...] * wob[o][kk*256+c] + boff[o]
__global__ __launch_bounds__(256) void off_gemm(const unsigned short* __restrict__ actP,
                                                const unsigned short* __restrict__ wob,
                                                const float* __restrict__ boff,
                                                float* __restrict__ offsP) {
  __shared__ unsigned short sA[64 * 64];  // 64 rows x 64 k
  __shared__ unsigned short sB[32 * 64];  // 32 o   x 64 k
  int tid = threadIdx.x, lane = tid & 63, wv = tid >> 6;
  int m0 = blockIdx.x * 64;
  int lane15 = lane & 15, quad8 = (lane >> 4) * 8;
  int rowA = tid >> 3;            // 0..31
  int kc = (tid & 7) * 8;         // k element offset within BK=64

  const unsigned short* baseA[2];
#pragma unroll
  for (int r = 0; r < 2; ++r) {
    int row = m0 + r * 32 + rowA;
    int b = row >> 12, p = row & 4095;
    baseA[r] = actP + (((size_t)(b * 68) + (p >> 6) + 2) * 68 + (p & 63) + 2) * 256 + kc;
  }
  const unsigned short* baseB = wob + (size_t)rowA * 2304 + kc;

  f32x4 acc[2] = {};
  for (int kk = 0; kk < 9; ++kk) {
    int shift = ((kk / 3) * 2 - 2) * 68 + ((kk % 3) * 2 - 2);
#pragma unroll 1
    for (int c0 = 0; c0 < 256; c0 += 64) {
      __syncthreads();
#pragma unroll
      for (int r = 0; r < 2; ++r) {
        const unsigned short* gp = baseA[r] + (long)shift * 256 + c0;
        __builtin_amdgcn_global_load_lds((const __attribute__((address_space(1))) void*)gp,
                                         (__attribute__((address_space(3))) void*)&sA[r * 2048 + wv * 512],
                                         16, 0, 0);
      }
      {
        const unsigned short* gp = baseB + kk * 256 + c0;
        __builtin_amdgcn_global_load_lds((const __attribute__((address_space(1))) void*)gp,
                                         (__attribute__((address_space(3))) void*)&sB[wv * 512],
                                         16, 0, 0);
      }
      __syncthreads();
      bf16x8 afr[2], bfr[2][2];
#pragma unroll
      for (int kq = 0; kq < 2; ++kq) {
        afr[kq] = *(const bf16x8*)&sA[(wv * 16 + lane15) * 64 + kq * 32 + quad8];
#pragma unroll
        for (int ni = 0; ni < 2; ++ni)
          bfr[kq][ni] = *(const bf16x8*)&sB[(ni * 16 + lane15) * 64 + kq * 32 + quad8];
      }
#pragma unroll
      for (int kq = 0; kq < 2; ++kq)
#pragma unroll
        for (int ni = 0; ni < 2; ++ni)
          acc[ni] = __builtin_amdgcn_mfma_f32_16x16x32_bf16(afr[kq], bfr[kq][ni], acc[ni], 0, 0, 0);
    }
  }

#pragma unroll
  for (int ni = 0; ni < 2; ++ni) {
    int o = ni * 16 + lane15;
    if (o < 18) {
      float bo = boff[o];
#pragma unroll
      for (int reg = 0; reg < 4; ++reg) {
        int row = m0 + wv * 16 + (lane >> 4) * 4 + reg;
        offsP[(size_t)row * 18 + o] = acc[ni][reg] + bo;
      }
    }
  }
}

// ---------------- bilinear im2col, vectorized: 32 lanes x 8ch per pixel ----------------
__global__ __launch_bounds__(256) void deform_sample(const unsigned short* __restrict__ act1T,
                                                     const float* __restrict__ offsP,
                                                     unsigned short* __restrict__ S) {
  int g = threadIdx.x >> 5, t = threadIdx.x & 31;
  int idx = blockIdx.x * 8 + g;     // global pixel index [0, 16384)
  int b = idx >> 12, p = idx & 4095;
  int h = p >> 6, w = p & 63;
  const unsigned short* actb = act1T + (size_t)b * 4096 * 256 + t * 8;
  unsigned short* Sp = S + (size_t)idx * 2304 + t * 8;
  float ov = (t < 18) ? offsP[(size_t)idx * 18 + t] : 0.f;
#pragma unroll
  for (int kk = 0; kk < 9; ++kk) {
    float offy = __shfl(ov, 2 * kk, 32);
    float offx = __shfl(ov, 2 * kk + 1, 32);
    float py = (float)(h + (kk / 3) * 2 - 2) + offy;
    float px = (float)(w + (kk % 3) * 2 - 2) + offx;
    float fy = floorf(py), fx = floorf(px);
    int y0 = (int)fy, x0 = (int)fx;
    float wy = py - fy, wx = px - fx;
    bool yv0 = (y0 >= 0 && y0 < 64), yv1 = (y0 >= -1 && y0 < 63);
    bool xv0 = (x0 >= 0 && x0 < 64), xv1 = (x0 >= -1 && x0 < 63);
    const unsigned short* cb = actb + (y0 * 64 + x0) * 256;
    uint4 q00{0,0,0,0}, q01{0,0,0,0}, q10{0,0,0,0}, q11{0,0,0,0};
    if (yv0 && xv0) q00 = *(const uint4*)(cb);
    if (yv0 && xv1) q01 = *(const uint4*)(cb + 256);
    if (yv1 && xv0) q10 = *(const uint4*)(cb + 64 * 256);
    if (yv1 && xv1) q11 = *(const uint4*)(cb + 64 * 256 + 256);
    float w00 = (1.f - wy) * (1.f - wx), w01 = (1.f - wy) * wx;
    float w10 = wy * (1.f - wx), w11 = wy * wx;
    unsigned u00[4] = {q00.x, q00.y, q00.z, q00.w};
    unsigned u01[4] = {q01.x, q01.y, q01.z, q01.w};
    unsigned u10[4] = {q10.x, q10.y, q10.z, q10.w};
    unsigned u11[4] = {q11.x, q11.y, q11.z, q11.w};
    unsigned out[4];
#pragma unroll
    for (int j = 0; j < 4; ++j) {
      float lo = bf2f((unsigned short)(u00[j] & 0xffffu)) * w00 +
                 bf2f((unsigned short)(u01[j] & 0xffffu)) * w01 +
                 bf2f((unsigned short)(u10[j] & 0xffffu)) * w10 +
                 bf2f((unsigned short)(u11[j] & 0xffffu)) * w11;
      float hi = bf2f((unsigned short)(u00[j] >> 16)) * w00 +
                 bf2f((unsigned short)(u01[j] >> 16)) * w01 +
                 bf2f((unsigned short)(u10[j] >> 16)) * w10 +
                 bf2f((unsigned short)(u11[j] >> 16)) * w11;
      out[j] = (unsigned)f2bf(lo) | ((unsigned)f2bf(hi) << 16);
    }
    *(uint4*)(Sp + kk * 256) = uint4{out[0], out[1], out[2], out[3]};
  }
}

extern "C" void kernel_launch(void* const* d_in, const int* in_sizes, int n_in,
                              void* d_out, int out_size, void* d_ws, size_t ws_size,
                              hipStream_t stream) {
  const float* x      = (const float*)d_in[0];
  const float* w1     = (const float*)d_in[1];
  const float* gamma1 = (const float*)d_in[2];
  const float* beta1  = (const float*)d_in[3];
  const float* mean1  = (const float*)d_in[4];
  const float* var1   = (const float*)d_in[5];
  const float* woff   = (const float*)d_in[6];
  const float* boff   = (const float*)d_in[7];
  const float* w2     = (const float*)d_in[8];
  const float* bconv2 = (const float*)d_in[9];
  const float* gamma2 = (const float*)d_in[10];
  const float* beta2  = (const float*)d_in[11];
  const float* mean2  = (const float*)d_in[12];
  const float* var2   = (const float*)d_in[13];
  const float* w3     = (const float*)d_in[14];
  const float* gamma3 = (const float*)d_in[15];
  const float* beta3  = (const float*)d_in[16];
  const float* mean3  = (const float*)d_in[17];
  const float* var3   = (const float*)d_in[18];

  char* ws = (char*)d_ws;
  unsigned short* xT    = (unsigned short*)(ws);                 // 33,554,432 B
  unsigned short* act1T = (unsigned short*)(ws + 33554432);      //  8,388,608
  unsigned short* act2T = (unsigned short*)(ws + 41943040);      //  8,388,608
  unsigned short* S     = (unsigned short*)(ws + 50331648);      // 75,497,472
  float*          offs  = (float*)(ws + 125829120);              //  1,179,648
  unsigned short* w1b   = (unsigned short*)(ws + 127008768);     //    524,288
  unsigned short* w2r   = (unsigned short*)(ws + 127533056);     //  1,179,648
  unsigned short* w3b   = (unsigned short*)(ws + 128712704);     //    524,288
  // aliased (non-overlapping lifetimes):
  unsigned short* act1P = S;                  // (B,68,68,256) bf16; dead before S written
  unsigned short* wob   = xT;                 // 147,456 B; written after gemm1 (xT dead)

  cvt_bf16<<<1024, 256, 0, stream>>>(w1, w1b, 262144);
  cvt_bf16<<<1024, 256, 0, stream>>>(w3, w3b, 262144);
  reorder_w2<<<2304, 256, 0, stream>>>(w2, w2r);
  zero16<<<2312, 256, 0, stream>>>((uint4*)act1P, 591872);
  transpose_x<<<dim3(128, 32, 4), 256, 0, stream>>>(x, xT);

  gemm_bt<1><<<dim3(2, 128, 1), 256, 0, stream>>>(xT, w1b, act1T, act1P, gamma1, beta1, mean1,
                                                  var1, nullptr, nullptr, 16384, 256, 1024, 0, 0);
  reorder_woff<<<288, 256, 0, stream>>>(woff, wob);
  off_gemm<<<256, 256, 0, stream>>>(act1P, wob, boff, offs);
  deform_sample<<<dim3(2048), 256, 0, stream>>>(act1T, offs, S);
  gemm_bt<2><<<dim3(2, 128, 1), 256, 0, stream>>>(S, w2r, act2T, nullptr, gamma2, beta2, mean2,
                                                  var2, bconv2, nullptr, 16384, 256, 2304, 0, 0);
  gemm_bt<3><<<dim3(32, 8, 4), 256, 0, stream>>>(w3b, act2T, d_out, nullptr, gamma3, beta3, mean3,
                                                 var3, nullptr, x, 1024, 4096, 256, 4096L * 256,
                                                 4194304L);
}

// Round 4
// 322.405 us; speedup vs baseline: 1.7055x; 1.0108x over previous
//
#include <hip/hip_runtime.h>

#define EPS_BN 1e-5f

typedef __bf16 bf16x8 __attribute__((ext_vector_type(8)));
typedef float f32x4 __attribute__((ext_vector_type(4)));

__device__ __forceinline__ unsigned short f2bf(float f) {
  union { float f; unsigned u; } v; v.f = f;
  unsigned r = v.u + 0x7fffu + ((v.u >> 16) & 1u);
  return (unsigned short)(r >> 16);
}
__device__ __forceinline__ float bf2f(unsigned short h) {
  union { unsigned u; float f; } v; v.u = ((unsigned)h) << 16;
  return v.f;
}

// ---------------- weight prep ----------------
__global__ void cvt_bf16(const float* __restrict__ in, unsigned short* __restrict__ out, int n) {
  int i = blockIdx.x * 256 + threadIdx.x;
  if (i < n) out[i] = f2bf(in[i]);
}

__global__ void zero16(uint4* __restrict__ p, int n16) {
  int i = blockIdx.x * 256 + threadIdx.x;
  if (i < n16) p[i] = uint4{0, 0, 0, 0};
}

// w2 (256,256,3,3) [o][c][kk] -> w2r [o][kk*256+c]  (bf16)
__global__ void reorder_w2(const float* __restrict__ w2, unsigned short* __restrict__ w2r) {
  int i = blockIdx.x * 256 + threadIdx.x;
  int o = i / 2304, r = i % 2304;
  int kk = r / 256, c = r % 256;
  w2r[i] = f2bf(w2[(size_t)o * 2304 + c * 9 + kk]);
}

// woff (18,256,3,3) -> wob [32][kk*256+c] bf16, rows 18..31 zero
__global__ void reorder_woff(const float* __restrict__ woff, unsigned short* __restrict__ wob) {
  int i = blockIdx.x * 256 + threadIdx.x;
  if (i >= 32 * 2304) return;
  int o = i / 2304, r = i % 2304;
  int kk = r / 256, c = r % 256;
  wob[i] = (o < 18) ? f2bf(woff[(size_t)o * 2304 + c * 9 + kk]) : (unsigned short)0;
}

// precompute folded BN: v*scale + shift
__global__ void prep_bn(const float* g1, const float* b1, const float* m1, const float* v1,
                        const float* g2, const float* b2, const float* m2, const float* v2,
                        const float* bconv2, float* s1, float* h1, float* s2, float* h2) {
  int c = threadIdx.x;
  float sc1 = rsqrtf(v1[c] + EPS_BN) * g1[c];
  s1[c] = sc1; h1[c] = b1[c] - m1[c] * sc1;
  float sc2 = rsqrtf(v2[c] + EPS_BN) * g2[c];
  s2[c] = sc2; h2[c] = b2[c] + (bconv2[c] - m2[c]) * sc2;
}

// ---------------- x transpose: (B,1024,4096) f32 -> (B*4096, 1024) bf16 ----------------
__global__ __launch_bounds__(256) void transpose_x(const float* __restrict__ x,
                                                   unsigned short* __restrict__ xT) {
  __shared__ float t[32][33];
  int b = blockIdx.z;
  int p0 = blockIdx.x * 32, c0 = blockIdx.y * 32;
  int tx = threadIdx.x & 31, ty = threadIdx.x >> 5;
  const float* xb = x + (size_t)b * 1024 * 4096;
#pragma unroll
  for (int j = 0; j < 4; ++j) {
    int c = c0 + ty + j * 8;
    t[ty + j * 8][tx] = xb[(size_t)c * 4096 + p0 + tx];
  }
  __syncthreads();
  unsigned short* xTb = xT + (size_t)b * 4096 * 1024;
#pragma unroll
  for (int j = 0; j < 4; ++j) {
    int p = p0 + ty + j * 8;
    xTb[(size_t)p * 1024 + c0 + tx] = f2bf(t[tx][ty + j * 8]);
  }
}

// ---------------- K-split MFMA GEMM: part[z][M][N] = A[M, zKH:(z+1)KH] * B[N, ...]^T ----------------
__global__ __launch_bounds__(256) void gemm_split(
    const unsigned short* __restrict__ A, const unsigned short* __restrict__ Bm,
    float* __restrict__ part, int M, int N, int K, int KH) {
  __shared__ unsigned short sA[128 * 32];
  __shared__ unsigned short sB[128 * 32];
  int tid = threadIdx.x, lane = tid & 63, wv = tid >> 6;
  int z = blockIdx.z;
  int m0 = blockIdx.y * 128, n0 = blockIdx.x * 128;
  f32x4 acc[4][4] = {};
  int rowA = tid >> 2;
  int kcol = (tid & 3) * 8;
  int wm = wv & 1, wn = wv >> 1;
  int lane15 = lane & 15, quad8 = (lane >> 4) * 8;
  int kend = z * KH + KH;

  for (int k0 = z * KH; k0 < kend; k0 += 32) {
    __syncthreads();
#pragma unroll
    for (int r = 0; r < 2; ++r) {
      const unsigned short* gp = A + (size_t)(m0 + r * 64 + rowA) * K + k0 + kcol;
      __builtin_amdgcn_global_load_lds((const __attribute__((address_space(1))) void*)gp,
                                       (__attribute__((address_space(3))) void*)&sA[r * 2048 + wv * 512],
                                       16, 0, 0);
    }
#pragma unroll
    for (int r = 0; r < 2; ++r) {
      const unsigned short* gp = Bm + (size_t)(n0 + r * 64 + rowA) * K + k0 + kcol;
      __builtin_amdgcn_global_load_lds((const __attribute__((address_space(1))) void*)gp,
                                       (__attribute__((address_space(3))) void*)&sB[r * 2048 + wv * 512],
                                       16, 0, 0);
    }
    __syncthreads();
    bf16x8 afr[4], bfr[4];
#pragma unroll
    for (int mi = 0; mi < 4; ++mi)
      afr[mi] = *(const bf16x8*)&sA[(wm * 64 + mi * 16 + lane15) * 32 + quad8];
#pragma unroll
    for (int ni = 0; ni < 4; ++ni)
      bfr[ni] = *(const bf16x8*)&sB[(wn * 64 + ni * 16 + lane15) * 32 + quad8];
#pragma unroll
    for (int mi = 0; mi < 4; ++mi)
#pragma unroll
      for (int ni = 0; ni < 4; ++ni)
        acc[mi][ni] = __builtin_amdgcn_mfma_f32_16x16x32_bf16(afr[mi], bfr[ni], acc[mi][ni], 0, 0, 0);
  }

  float* outF = part + (size_t)z * M * N;
#pragma unroll
  for (int mi = 0; mi < 4; ++mi) {
#pragma unroll
    for (int ni = 0; ni < 4; ++ni) {
      int col = n0 + wn * 64 + ni * 16 + lane15;
#pragma unroll
      for (int reg = 0; reg < 4; ++reg) {
        int row = m0 + wm * 64 + mi * 16 + (lane >> 4) * 4 + reg;
        outF[(size_t)row * N + col] = acc[mi][ni][reg];
      }
    }
  }
}

// ---------------- epilogue: sum 2 partials, folded BN + ReLU -> bf16 (+opt padded copy) ----------------
template <int PAD>
__global__ __launch_bounds__(256) void epi_bn(const float* __restrict__ part,
                                              const float* __restrict__ scale,
                                              const float* __restrict__ shift,
                                              unsigned short* __restrict__ outT,
                                              unsigned short* __restrict__ outP) {
  int gid = blockIdx.x * 256 + threadIdx.x;   // 16384*32
  int row = gid >> 5, c0 = (gid & 31) * 8;
  const float* a = part + (size_t)row * 256 + c0;
  const float* b = a + (size_t)16384 * 256;
  float va[8], vb[8], sc[8], sh[8];
  *(float4*)&va[0] = *(const float4*)a;       *(float4*)&va[4] = *(const float4*)(a + 4);
  *(float4*)&vb[0] = *(const float4*)b;       *(float4*)&vb[4] = *(const float4*)(b + 4);
  *(float4*)&sc[0] = *(const float4*)(scale + c0); *(float4*)&sc[4] = *(const float4*)(scale + c0 + 4);
  *(float4*)&sh[0] = *(const float4*)(shift + c0); *(float4*)&sh[4] = *(const float4*)(shift + c0 + 4);
  unsigned o[4];
#pragma unroll
  for (int j = 0; j < 4; ++j) {
    float lo = fmaxf((va[2 * j] + vb[2 * j]) * sc[2 * j] + sh[2 * j], 0.f);
    float hi = fmaxf((va[2 * j + 1] + vb[2 * j + 1]) * sc[2 * j + 1] + sh[2 * j + 1], 0.f);
    o[j] = (unsigned)f2bf(lo) | ((unsigned)f2bf(hi) << 16);
  }
  uint4 pk{o[0], o[1], o[2], o[3]};
  *(uint4*)(outT + (size_t)row * 256 + c0) = pk;
  if constexpr (PAD) {
    int bb = row >> 12, p = row & 4095;
    *(uint4*)(outP + (((size_t)(bb * 68) + (p >> 6) + 2) * 68 + (p & 63) + 2) * 256 + c0) = pk;
  }
}

// ---------------- final GEMM (1x1 conv #3) + BN + residual + ReLU, f32 out ----------------
__global__ __launch_bounds__(256) void gemm_res(
    const unsigned short* __restrict__ A, const unsigned short* __restrict__ Bm,
    float* __restrict__ outp, const float* __restrict__ gamma, const float* __restrict__ beta,
    const float* __restrict__ mean, const float* __restrict__ var,
    const float* __restrict__ resid, int M, int N, int K, long bStrideB, long bStrideOut) {
  __shared__ unsigned short sA[128 * 32];
  __shared__ unsigned short sB[128 * 32];
  int tid = threadIdx.x, lane = tid & 63, wv = tid >> 6;
  int z = blockIdx.z;
  const unsigned short* Bz = Bm + (size_t)z * bStrideB;
  int m0 = blockIdx.y * 128, n0 = blockIdx.x * 128;
  f32x4 acc[4][4] = {};
  int rowA = tid >> 2;
  int kcol = (tid & 3) * 8;
  int wm = wv & 1, wn = wv >> 1;
  int lane15 = lane & 15, quad8 = (lane >> 4) * 8;

  for (int k0 = 0; k0 < K; k0 += 32) {
    __syncthreads();
#pragma unroll
    for (int r = 0; r < 2; ++r) {
      const unsigned short* gp = A + (size_t)(m0 + r * 64 + rowA) * K + k0 + kcol;
      __builtin_amdgcn_global_load_lds((const __attribute__((address_space(1))) void*)gp,
                                       (__attribute__((address_space(3))) void*)&sA[r * 2048 + wv * 512],
                                       16, 0, 0);
    }
#pragma unroll
    for (int r = 0; r < 2; ++r) {
      const unsigned short* gp = Bz + (size_t)(n0 + r * 64 + rowA) * K + k0 + kcol;
      __builtin_amdgcn_global_load_lds((const __attribute__((address_space(1))) void*)gp,
                                       (__attribute__((address_space(3))) void*)&sB[r * 2048 + wv * 512],
                                       16, 0, 0);
    }
    __syncthreads();
    bf16x8 afr[4], bfr[4];
#pragma unroll
    for (int mi = 0; mi < 4; ++mi)
      afr[mi] = *(const bf16x8*)&sA[(wm * 64 + mi * 16 + lane15) * 32 + quad8];
#pragma unroll
    for (int ni = 0; ni < 4; ++ni)
      bfr[ni] = *(const bf16x8*)&sB[(wn * 64 + ni * 16 + lane15) * 32 + quad8];
#pragma unroll
    for (int mi = 0; mi < 4; ++mi)
#pragma unroll
      for (int ni = 0; ni < 4; ++ni)
        acc[mi][ni] = __builtin_amdgcn_mfma_f32_16x16x32_bf16(afr[mi], bfr[ni], acc[mi][ni], 0, 0, 0);
  }

  float* outF = outp + (size_t)z * bStrideOut;
  const float* res = resid + (size_t)z * bStrideOut;
#pragma unroll
  for (int mi = 0; mi < 4; ++mi) {
#pragma unroll
    for (int ni = 0; ni < 4; ++ni) {
      int col = n0 + wn * 64 + ni * 16 + lane15;
#pragma unroll
      for (int reg = 0; reg < 4; ++reg) {
        int row = m0 + wm * 64 + mi * 16 + (lane >> 4) * 4 + reg;
        int ch = row;
        float inv = rsqrtf(var[ch] + EPS_BN) * gamma[ch];
        float v = (acc[mi][ni][reg] - mean[ch]) * inv + beta[ch];
        v += res[(size_t)row * N + col];
        outF[(size_t)row * N + col] = fmaxf(v, 0.f);
      }
    }
  }
}

// ---------------- offset conv as MFMA GEMM over padded act1P ----------------
__global__ __launch_bounds__(256) void off_gemm(const unsigned short* __restrict__ actP,
                                                const unsigned short* __restrict__ wob,
                                                const float* __restrict__ boff,
                                                float* __restrict__ offsP) {
  __shared__ unsigned short sA[64 * 64];
  __shared__ unsigned short sB[32 * 64];
  int tid = threadIdx.x, lane = tid & 63, wv = tid >> 6;
  int m0 = blockIdx.x * 64;
  int lane15 = lane & 15, quad8 = (lane >> 4) * 8;
  int rowA = tid >> 3;
  int kc = (tid & 7) * 8;

  const unsigned short* baseA[2];
#pragma unroll
  for (int r = 0; r < 2; ++r) {
    int row = m0 + r * 32 + rowA;
    int b = row >> 12, p = row & 4095;
    baseA[r] = actP + (((size_t)(b * 68) + (p >> 6) + 2) * 68 + (p & 63) + 2) * 256 + kc;
  }
  const unsigned short* baseB = wob + (size_t)rowA * 2304 + kc;

  f32x4 acc[2] = {};
  for (int kk = 0; kk < 9; ++kk) {
    int shift = ((kk / 3) * 2 - 2) * 68 + ((kk % 3) * 2 - 2);
#pragma unroll 1
    for (int c0 = 0; c0 < 256; c0 += 64) {
      __syncthreads();
#pragma unroll
      for (int r = 0; r < 2; ++r) {
        const unsigned short* gp = baseA[r] + (long)shift * 256 + c0;
        __builtin_amdgcn_global_load_lds((const __attribute__((address_space(1))) void*)gp,
                                         (__attribute__((address_space(3))) void*)&sA[r * 2048 + wv * 512],
                                         16, 0, 0);
      }
      {
        const unsigned short* gp = baseB + kk * 256 + c0;
        __builtin_amdgcn_global_load_lds((const __attribute__((address_space(1))) void*)gp,
                                         (__attribute__((address_space(3))) void*)&sB[wv * 512],
                                         16, 0, 0);
      }
      __syncthreads();
      bf16x8 afr[2], bfr[2][2];
#pragma unroll
      for (int kq = 0; kq < 2; ++kq) {
        afr[kq] = *(const bf16x8*)&sA[(wv * 16 + lane15) * 64 + kq * 32 + quad8];
#pragma unroll
        for (int ni = 0; ni < 2; ++ni)
          bfr[kq][ni] = *(const bf16x8*)&sB[(ni * 16 + lane15) * 64 + kq * 32 + quad8];
      }
#pragma unroll
      for (int kq = 0; kq < 2; ++kq)
#pragma unroll
        for (int ni = 0; ni < 2; ++ni)
          acc[ni] = __builtin_amdgcn_mfma_f32_16x16x32_bf16(afr[kq], bfr[kq][ni], acc[ni], 0, 0, 0);
    }
  }

#pragma unroll
  for (int ni = 0; ni < 2; ++ni) {
    int o = ni * 16 + lane15;
    if (o < 18) {
      float bo = boff[o];
#pragma unroll
      for (int reg = 0; reg < 4; ++reg) {
        int row = m0 + wv * 16 + (lane >> 4) * 4 + reg;
        offsP[(size_t)row * 18 + o] = acc[ni][reg] + bo;
      }
    }
  }
}

// ---------------- bilinear im2col, vectorized: 32 lanes x 8ch per pixel ----------------
__global__ __launch_bounds__(256) void deform_sample(const unsigned short* __restrict__ act1T,
                                                     const float* __restrict__ offsP,
                                                     unsigned short* __restrict__ S) {
  int g = threadIdx.x >> 5, t = threadIdx.x & 31;
  int idx = blockIdx.x * 8 + g;
  int b = idx >> 12, p = idx & 4095;
  int h = p >> 6, w = p & 63;
  const unsigned short* actb = act1T + (size_t)b * 4096 * 256 + t * 8;
  unsigned short* Sp = S + (size_t)idx * 2304 + t * 8;
  float ov = (t < 18) ? offsP[(size_t)idx * 18 + t] : 0.f;
#pragma unroll
  for (int kk = 0; kk < 9; ++kk) {
    float offy = __shfl(ov, 2 * kk, 32);
    float offx = __shfl(ov, 2 * kk + 1, 32);
    float py = (float)(h + (kk / 3) * 2 - 2) + offy;
    float px = (float)(w + (kk % 3) * 2 - 2) + offx;
    float fy = floorf(py), fx = floorf(px);
    int y0 = (int)fy, x0 = (int)fx;
    float wy = py - fy, wx = px - fx;
    bool yv0 = (y0 >= 0 && y0 < 64), yv1 = (y0 >= -1 && y0 < 63);
    bool xv0 = (x0 >= 0 && x0 < 64), xv1 = (x0 >= -1 && x0 < 63);
    const unsigned short* cb = actb + (y0 * 64 + x0) * 256;
    uint4 q00{0,0,0,0}, q01{0,0,0,0}, q10{0,0,0,0}, q11{0,0,0,0};
    if (yv0 && xv0) q00 = *(const uint4*)(cb);
    if (yv0 && xv1) q01 = *(const uint4*)(cb + 256);
    if (yv1 && xv0) q10 = *(const uint4*)(cb + 64 * 256);
    if (yv1 && xv1) q11 = *(const uint4*)(cb + 64 * 256 + 256);
    float w00 = (1.f - wy) * (1.f - wx), w01 = (1.f - wy) * wx;
    float w10 = wy * (1.f - wx), w11 = wy * wx;
    unsigned u00[4] = {q00.x, q00.y, q00.z, q00.w};
    unsigned u01[4] = {q01.x, q01.y, q01.z, q01.w};
    unsigned u10[4] = {q10.x, q10.y, q10.z, q10.w};
    unsigned u11[4] = {q11.x, q11.y, q11.z, q11.w};
    unsigned out[4];
#pragma unroll
    for (int j = 0; j < 4; ++j) {
      float lo = bf2f((unsigned short)(u00[j] & 0xffffu)) * w00 +
                 bf2f((unsigned short)(u01[j] & 0xffffu)) * w01 +
                 bf2f((unsigned short)(u10[j] & 0xffffu)) * w10 +
                 bf2f((unsigned short)(u11[j] & 0xffffu)) * w11;
      float hi = bf2f((unsigned short)(u00[j] >> 16)) * w00 +
                 bf2f((unsigned short)(u01[j] >> 16)) * w01 +
                 bf2f((unsigned short)(u10[j] >> 16)) * w10 +
                 bf2f((unsigned short)(u11[j] >> 16)) * w11;
      out[j] = (unsigned)f2bf(lo) | ((unsigned)f2bf(hi) << 16);
    }
    *(uint4*)(Sp + kk * 256) = uint4{out[0], out[1], out[2], out[3]};
  }
}

extern "C" void kernel_launch(void* const* d_in, const int* in_sizes, int n_in,
                              void* d_out, int out_size, void* d_ws, size_t ws_size,
                              hipStream_t stream) {
  const float* x      = (const float*)d_in[0];
  const float* w1     = (const float*)d_in[1];
  const float* gamma1 = (const float*)d_in[2];
  const float* beta1  = (const float*)d_in[3];
  const float* mean1  = (const float*)d_in[4];
  const float* var1   = (const float*)d_in[5];
  const float* woff   = (const float*)d_in[6];
  const float* boff   = (const float*)d_in[7];
  const float* w2     = (const float*)d_in[8];
  const float* bconv2 = (const float*)d_in[9];
  const float* gamma2 = (const float*)d_in[10];
  const float* beta2  = (const float*)d_in[11];
  const float* mean2  = (const float*)d_in[12];
  const float* var2   = (const float*)d_in[13];
  const float* w3     = (const float*)d_in[14];
  const float* gamma3 = (const float*)d_in[15];
  const float* beta3  = (const float*)d_in[16];
  const float* mean3  = (const float*)d_in[17];
  const float* var3   = (const float*)d_in[18];

  char* ws = (char*)d_ws;
  unsigned short* xT    = (unsigned short*)(ws);                 // 33,554,432 B
  unsigned short* act1T = (unsigned short*)(ws + 33554432);      //  8,388,608
  unsigned short* act2T = (unsigned short*)(ws + 41943040);      //  8,388,608
  unsigned short* S     = (unsigned short*)(ws + 50331648);      // 75,497,472 (ends 125,829,120)
  float*          offs  = (float*)(ws + 125829120);              //  1,179,648
  unsigned short* w1b   = (unsigned short*)(ws + 127008768);     //    524,288
  unsigned short* w2r   = (unsigned short*)(ws + 127533056);     //  1,179,648
  unsigned short* w3b   = (unsigned short*)(ws + 128712704);     //    524,288
  float*          bnS1  = (float*)(ws + 129236992);              //      1,024
  float*          bnH1  = (float*)(ws + 129238016);              //      1,024
  float*          bnS2  = (float*)(ws + 129239040);              //      1,024
  float*          bnH2  = (float*)(ws + 129240064);              //      1,024
  // aliased (non-overlapping lifetimes):
  unsigned short* act1P = S;                         // 9,469,952 B at S base; dead before S written
  float*          part1 = (float*)(ws + 62914560);   // 33,554,432 B inside S region, after act1P
  float*          part2 = (float*)ws;                // 33,554,432 B in xT region (xT dead post-GEMM1)
  unsigned short* wob   = xT;                        // 147,456 B; live only reorder_woff..off_gemm

  cvt_bf16<<<1024, 256, 0, stream>>>(w1, w1b, 262144);
  cvt_bf16<<<1024, 256, 0, stream>>>(w3, w3b, 262144);
  reorder_w2<<<2304, 256, 0, stream>>>(w2, w2r);
  zero16<<<2312, 256, 0, stream>>>((uint4*)act1P, 591872);
  prep_bn<<<1, 256, 0, stream>>>(gamma1, beta1, mean1, var1, gamma2, beta2, mean2, var2,
                                 bconv2, bnS1, bnH1, bnS2, bnH2);
  transpose_x<<<dim3(128, 32, 4), 256, 0, stream>>>(x, xT);

  // GEMM1 (K=1024) split x2 -> fp32 partials -> BN1+ReLU epilogue (act1T + padded act1P)
  gemm_split<<<dim3(2, 128, 2), 256, 0, stream>>>(xT, w1b, part1, 16384, 256, 1024, 512);
  epi_bn<1><<<2048, 256, 0, stream>>>(part1, bnS1, bnH1, act1T, act1P);

  reorder_woff<<<288, 256, 0, stream>>>(woff, wob);
  off_gemm<<<256, 256, 0, stream>>>(act1P, wob, boff, offs);
  deform_sample<<<dim3(2048), 256, 0, stream>>>(act1T, offs, S);

  // GEMM2 (K=2304) split x2 -> fp32 partials -> bias+BN2+ReLU epilogue
  gemm_split<<<dim3(2, 128, 2), 256, 0, stream>>>(S, w2r, part2, 16384, 256, 2304, 1152);
  epi_bn<0><<<2048, 256, 0, stream>>>(part2, bnS2, bnH2, act2T, nullptr);

  // GEMM3: out = relu(bn3(w3 @ act2T^T) + x)
  gemm_res<<<dim3(32, 8, 4), 256, 0, stream>>>(w3b, act2T, (float*)d_out, gamma3, beta3, mean3,
                                               var3, x, 1024, 4096, 256, 4096L * 256, 4194304L);
}

// Round 5
// 316.507 us; speedup vs baseline: 1.7373x; 1.0186x over previous
//
#include <hip/hip_runtime.h>

#define EPS_BN 1e-5f

typedef __bf16 bf16x8 __attribute__((ext_vector_type(8)));
typedef float f32x4 __attribute__((ext_vector_type(4)));

__device__ __forceinline__ unsigned short f2bf(float f) {
  union { float f; unsigned u; } v; v.f = f;
  unsigned r = v.u + 0x7fffu + ((v.u >> 16) & 1u);
  return (unsigned short)(r >> 16);
}
__device__ __forceinline__ float bf2f(unsigned short h) {
  union { unsigned u; float f; } v; v.u = ((unsigned)h) << 16;
  return v.f;
}

// ---------------- weight prep ----------------
__global__ void cvt_bf16(const float* __restrict__ in, unsigned short* __restrict__ out, int n) {
  int i = blockIdx.x * 256 + threadIdx.x;
  if (i < n) out[i] = f2bf(in[i]);
}

__global__ void zero16(uint4* __restrict__ p, int n16) {
  int i = blockIdx.x * 256 + threadIdx.x;
  if (i < n16) p[i] = uint4{0, 0, 0, 0};
}

// w2 (256,256,3,3) [o][c][kk] -> w2r [o][kk*256+c]  (bf16)
__global__ void reorder_w2(const float* __restrict__ w2, unsigned short* __restrict__ w2r) {
  int i = blockIdx.x * 256 + threadIdx.x;
  int o = i / 2304, r = i % 2304;
  int kk = r / 256, c = r % 256;
  w2r[i] = f2bf(w2[(size_t)o * 2304 + c * 9 + kk]);
}

// woff (18,256,3,3) -> wob [32][kk*256+c] bf16, rows 18..31 zero
__global__ void reorder_woff(const float* __restrict__ woff, unsigned short* __restrict__ wob) {
  int i = blockIdx.x * 256 + threadIdx.x;
  if (i >= 32 * 2304) return;
  int o = i / 2304, r = i % 2304;
  int kk = r / 256, c = r % 256;
  wob[i] = (o < 18) ? f2bf(woff[(size_t)o * 2304 + c * 9 + kk]) : (unsigned short)0;
}

// folded BN for layers 1/2: v*scale + shift
__global__ void prep_bn(const float* g1, const float* b1, const float* m1, const float* v1,
                        const float* g2, const float* b2, const float* m2, const float* v2,
                        const float* bconv2, float* s1, float* h1, float* s2, float* h2) {
  int c = threadIdx.x;
  float sc1 = rsqrtf(v1[c] + EPS_BN) * g1[c];
  s1[c] = sc1; h1[c] = b1[c] - m1[c] * sc1;
  float sc2 = rsqrtf(v2[c] + EPS_BN) * g2[c];
  s2[c] = sc2; h2[c] = b2[c] + (bconv2[c] - m2[c]) * sc2;
}

// BN3 scale/shift over 1024 channels
__global__ void prep_bn3(const float* __restrict__ g, const float* __restrict__ b,
                         const float* __restrict__ m, const float* __restrict__ v,
                         float* __restrict__ scale, float* __restrict__ shift) {
  int c = blockIdx.x * 256 + threadIdx.x;
  float sc = rsqrtf(v[c] + EPS_BN) * g[c];
  scale[c] = sc;
  shift[c] = b[c] - m[c] * sc;
}

// w3 (1024,256) f32 -> bf16 with BN3 scale folded per output channel (row)
__global__ void cvt_w3s(const float* __restrict__ w3, const float* __restrict__ scale,
                        unsigned short* __restrict__ out) {
  int i = blockIdx.x * 256 + threadIdx.x;  // 1024*256
  out[i] = f2bf(w3[i] * scale[i >> 8]);
}

// ---------------- x transpose: (B,1024,4096) f32 -> (B*4096, 1024) bf16 ----------------
__global__ __launch_bounds__(256) void transpose_x(const float* __restrict__ x,
                                                   unsigned short* __restrict__ xT) {
  __shared__ float t[32][33];
  int b = blockIdx.z;
  int p0 = blockIdx.x * 32, c0 = blockIdx.y * 32;
  int tx = threadIdx.x & 31, ty = threadIdx.x >> 5;
  const float* xb = x + (size_t)b * 1024 * 4096;
#pragma unroll
  for (int j = 0; j < 4; ++j) {
    int c = c0 + ty + j * 8;
    t[ty + j * 8][tx] = xb[(size_t)c * 4096 + p0 + tx];
  }
  __syncthreads();
  unsigned short* xTb = xT + (size_t)b * 4096 * 1024;
#pragma unroll
  for (int j = 0; j < 4; ++j) {
    int p = p0 + ty + j * 8;
    xTb[(size_t)p * 1024 + c0 + tx] = f2bf(t[tx][ty + j * 8]);
  }
}

// ---------------- K-split MFMA GEMM: part[z][M][N] = A[M, zKH:(z+1)KH] * B[N, ...]^T ----------------
__global__ __launch_bounds__(256) void gemm_split(
    const unsigned short* __restrict__ A, const unsigned short* __restrict__ Bm,
    float* __restrict__ part, int M, int N, int K, int KH) {
  __shared__ unsigned short sA[128 * 32];
  __shared__ unsigned short sB[128 * 32];
  int tid = threadIdx.x, lane = tid & 63, wv = tid >> 6;
  int z = blockIdx.z;
  int m0 = blockIdx.y * 128, n0 = blockIdx.x * 128;
  f32x4 acc[4][4] = {};
  int rowA = tid >> 2;
  int kcol = (tid & 3) * 8;
  int wm = wv & 1, wn = wv >> 1;
  int lane15 = lane & 15, quad8 = (lane >> 4) * 8;
  int kend = z * KH + KH;

  for (int k0 = z * KH; k0 < kend; k0 += 32) {
    __syncthreads();
#pragma unroll
    for (int r = 0; r < 2; ++r) {
      const unsigned short* gp = A + (size_t)(m0 + r * 64 + rowA) * K + k0 + kcol;
      __builtin_amdgcn_global_load_lds((const __attribute__((address_space(1))) void*)gp,
                                       (__attribute__((address_space(3))) void*)&sA[r * 2048 + wv * 512],
                                       16, 0, 0);
    }
#pragma unroll
    for (int r = 0; r < 2; ++r) {
      const unsigned short* gp = Bm + (size_t)(n0 + r * 64 + rowA) * K + k0 + kcol;
      __builtin_amdgcn_global_load_lds((const __attribute__((address_space(1))) void*)gp,
                                       (__attribute__((address_space(3))) void*)&sB[r * 2048 + wv * 512],
                                       16, 0, 0);
    }
    __syncthreads();
    bf16x8 afr[4], bfr[4];
#pragma unroll
    for (int mi = 0; mi < 4; ++mi)
      afr[mi] = *(const bf16x8*)&sA[(wm * 64 + mi * 16 + lane15) * 32 + quad8];
#pragma unroll
    for (int ni = 0; ni < 4; ++ni)
      bfr[ni] = *(const bf16x8*)&sB[(wn * 64 + ni * 16 + lane15) * 32 + quad8];
#pragma unroll
    for (int mi = 0; mi < 4; ++mi)
#pragma unroll
      for (int ni = 0; ni < 4; ++ni)
        acc[mi][ni] = __builtin_amdgcn_mfma_f32_16x16x32_bf16(afr[mi], bfr[ni], acc[mi][ni], 0, 0, 0);
  }

  float* outF = part + (size_t)z * M * N;
#pragma unroll
  for (int mi = 0; mi < 4; ++mi) {
#pragma unroll
    for (int ni = 0; ni < 4; ++ni) {
      int col = n0 + wn * 64 + ni * 16 + lane15;
#pragma unroll
      for (int reg = 0; reg < 4; ++reg) {
        int row = m0 + wm * 64 + mi * 16 + (lane >> 4) * 4 + reg;
        outF[(size_t)row * N + col] = acc[mi][ni][reg];
      }
    }
  }
}

// ---------------- epilogue: sum 2 partials, folded BN + ReLU -> bf16 (+opt padded copy) ----------------
template <int PAD>
__global__ __launch_bounds__(256) void epi_bn(const float* __restrict__ part,
                                              const float* __restrict__ scale,
                                              const float* __restrict__ shift,
                                              unsigned short* __restrict__ outT,
                                              unsigned short* __restrict__ outP) {
  int gid = blockIdx.x * 256 + threadIdx.x;   // 16384*32
  int row = gid >> 5, c0 = (gid & 31) * 8;
  const float* a = part + (size_t)row * 256 + c0;
  const float* b = a + (size_t)16384 * 256;
  float va[8], vb[8], sc[8], sh[8];
  *(float4*)&va[0] = *(const float4*)a;       *(float4*)&va[4] = *(const float4*)(a + 4);
  *(float4*)&vb[0] = *(const float4*)b;       *(float4*)&vb[4] = *(const float4*)(b + 4);
  *(float4*)&sc[0] = *(const float4*)(scale + c0); *(float4*)&sc[4] = *(const float4*)(scale + c0 + 4);
  *(float4*)&sh[0] = *(const float4*)(shift + c0); *(float4*)&sh[4] = *(const float4*)(shift + c0 + 4);
  unsigned o[4];
#pragma unroll
  for (int j = 0; j < 4; ++j) {
    float lo = fmaxf((va[2 * j] + vb[2 * j]) * sc[2 * j] + sh[2 * j], 0.f);
    float hi = fmaxf((va[2 * j + 1] + vb[2 * j + 1]) * sc[2 * j + 1] + sh[2 * j + 1], 0.f);
    o[j] = (unsigned)f2bf(lo) | ((unsigned)f2bf(hi) << 16);
  }
  uint4 pk{o[0], o[1], o[2], o[3]};
  *(uint4*)(outT + (size_t)row * 256 + c0) = pk;
  if constexpr (PAD) {
    int bb = row >> 12, p = row & 4095;
    *(uint4*)(outP + (((size_t)(bb * 68) + (p >> 6) + 2) * 68 + (p & 63) + 2) * 256 + c0) = pk;
  }
}

// ---------------- final GEMM (1x1 conv #3), BN3 pre-folded into weights ----------------
// out = relu(acc + shift3[row] + resid);  vectorized epilogue via LDS transpose
__global__ __launch_bounds__(256) void gemm_res(
    const unsigned short* __restrict__ A, const unsigned short* __restrict__ Bm,
    float* __restrict__ outp, const float* __restrict__ shift3,
    const float* __restrict__ resid, int M, int N, int K, long bStrideB, long bStrideOut) {
  __shared__ unsigned short sA[128 * 32];
  __shared__ unsigned short sB[128 * 32];
  __shared__ float tbuf[32 * 132];
  int tid = threadIdx.x, lane = tid & 63, wv = tid >> 6;
  int z = blockIdx.z;
  const unsigned short* Bz = Bm + (size_t)z * bStrideB;
  int m0 = blockIdx.y * 128, n0 = blockIdx.x * 128;
  f32x4 acc[4][4] = {};
  int rowA = tid >> 2;
  int kcol = (tid & 3) * 8;
  int wm = wv & 1, wn = wv >> 1;
  int lane15 = lane & 15, quad8 = (lane >> 4) * 8, quad = lane >> 4;

  for (int k0 = 0; k0 < K; k0 += 32) {
    __syncthreads();
#pragma unroll
    for (int r = 0; r < 2; ++r) {
      const unsigned short* gp = A + (size_t)(m0 + r * 64 + rowA) * K + k0 + kcol;
      __builtin_amdgcn_global_load_lds((const __attribute__((address_space(1))) void*)gp,
                                       (__attribute__((address_space(3))) void*)&sA[r * 2048 + wv * 512],
                                       16, 0, 0);
    }
#pragma unroll
    for (int r = 0; r < 2; ++r) {
      const unsigned short* gp = Bz + (size_t)(n0 + r * 64 + rowA) * K + k0 + kcol;
      __builtin_amdgcn_global_load_lds((const __attribute__((address_space(1))) void*)gp,
                                       (__attribute__((address_space(3))) void*)&sB[r * 2048 + wv * 512],
                                       16, 0, 0);
    }
    __syncthreads();
    bf16x8 afr[4], bfr[4];
#pragma unroll
    for (int mi = 0; mi < 4; ++mi)
      afr[mi] = *(const bf16x8*)&sA[(wm * 64 + mi * 16 + lane15) * 32 + quad8];
#pragma unroll
    for (int ni = 0; ni < 4; ++ni)
      bfr[ni] = *(const bf16x8*)&sB[(wn * 64 + ni * 16 + lane15) * 32 + quad8];
#pragma unroll
    for (int mi = 0; mi < 4; ++mi)
#pragma unroll
      for (int ni = 0; ni < 4; ++ni)
        acc[mi][ni] = __builtin_amdgcn_mfma_f32_16x16x32_bf16(afr[mi], bfr[ni], acc[mi][ni], 0, 0, 0);
  }

  float* outF = outp + (size_t)z * bStrideOut;
  const float* res = resid + (size_t)z * bStrideOut;
  int trow = tid >> 3;            // 0..31 (chunk-local row)
  int tcol = (tid & 7) * 4;       // 0..28
  int growBase = m0 + (trow >> 4) * 64 + (trow & 15);
#pragma unroll
  for (int mi = 0; mi < 4; ++mi) {
    __syncthreads();
#pragma unroll
    for (int ni = 0; ni < 4; ++ni)
#pragma unroll
      for (int reg = 0; reg < 4; ++reg)
        tbuf[(wm * 16 + quad * 4 + reg) * 132 + wn * 64 + ni * 16 + lane15] = acc[mi][ni][reg];
    __syncthreads();
    int gr = growBase + mi * 16;
    float sh = shift3[gr];
    const float* rp = res + (size_t)gr * N + n0 + tcol;
    float* op = outF + (size_t)gr * N + n0 + tcol;
    const float* lp = &tbuf[trow * 132 + tcol];
#pragma unroll
    for (int j = 0; j < 4; ++j) {
      float4 rv = *(const float4*)(rp + j * 32);
      float4 lv = *(const float4*)(lp + j * 32);
      float4 ov;
      ov.x = fmaxf(lv.x + sh + rv.x, 0.f);
      ov.y = fmaxf(lv.y + sh + rv.y, 0.f);
      ov.z = fmaxf(lv.z + sh + rv.z, 0.f);
      ov.w = fmaxf(lv.w + sh + rv.w, 0.f);
      *(float4*)(op + j * 32) = ov;
    }
  }
}

// ---------------- offset conv as MFMA GEMM over padded act1P ----------------
__global__ __launch_bounds__(256) void off_gemm(const unsigned short* __restrict__ actP,
                                                const unsigned short* __restrict__ wob,
                                                const float* __restrict__ boff,
                                                float* __restrict__ offsP) {
  __shared__ unsigned short sA[64 * 64];
  __shared__ unsigned short sB[32 * 64];
  int tid = threadIdx.x, lane = tid & 63, wv = tid >> 6;
  int m0 = blockIdx.x * 64;
  int lane15 = lane & 15, quad8 = (lane >> 4) * 8;
  int rowA = tid >> 3;
  int kc = (tid & 7) * 8;

  const unsigned short* baseA[2];
#pragma unroll
  for (int r = 0; r < 2; ++r) {
    int row = m0 + r * 32 + rowA;
    int b = row >> 12, p = row & 4095;
    baseA[r] = actP + (((size_t)(b * 68) + (p >> 6) + 2) * 68 + (p & 63) + 2) * 256 + kc;
  }
  const unsigned short* baseB = wob + (size_t)rowA * 2304 + kc;

  f32x4 acc[2] = {};
  for (int kk = 0; kk < 9; ++kk) {
    int shift = ((kk / 3) * 2 - 2) * 68 + ((kk % 3) * 2 - 2);
#pragma unroll 1
    for (int c0 = 0; c0 < 256; c0 += 64) {
      __syncthreads();
#pragma unroll
      for (int r = 0; r < 2; ++r) {
        const unsigned short* gp = baseA[r] + (long)shift * 256 + c0;
        __builtin_amdgcn_global_load_lds((const __attribute__((address_space(1))) void*)gp,
                                         (__attribute__((address_space(3))) void*)&sA[r * 2048 + wv * 512],
                                         16, 0, 0);
      }
      {
        const unsigned short* gp = baseB + kk * 256 + c0;
        __builtin_amdgcn_global_load_lds((const __attribute__((address_space(1))) void*)gp,
                                         (__attribute__((address_space(3))) void*)&sB[wv * 512],
                                         16, 0, 0);
      }
      __syncthreads();
      bf16x8 afr[2], bfr[2][2];
#pragma unroll
      for (int kq = 0; kq < 2; ++kq) {
        afr[kq] = *(const bf16x8*)&sA[(wv * 16 + lane15) * 64 + kq * 32 + quad8];
#pragma unroll
        for (int ni = 0; ni < 2; ++ni)
          bfr[kq][ni] = *(const bf16x8*)&sB[(ni * 16 + lane15) * 64 + kq * 32 + quad8];
      }
#pragma unroll
      for (int kq = 0; kq < 2; ++kq)
#pragma unroll
        for (int ni = 0; ni < 2; ++ni)
          acc[ni] = __builtin_amdgcn_mfma_f32_16x16x32_bf16(afr[kq], bfr[kq][ni], acc[ni], 0, 0, 0);
    }
  }

#pragma unroll
  for (int ni = 0; ni < 2; ++ni) {
    int o = ni * 16 + lane15;
    if (o < 18) {
      float bo = boff[o];
#pragma unroll
      for (int reg = 0; reg < 4; ++reg) {
        int row = m0 + wv * 16 + (lane >> 4) * 4 + reg;
        offsP[(size_t)row * 18 + o] = acc[ni][reg] + bo;
      }
    }
  }
}

// ---------------- bilinear im2col, vectorized: 32 lanes x 8ch per pixel ----------------
__global__ __launch_bounds__(256) void deform_sample(const unsigned short* __restrict__ act1T,
                                                     const float* __restrict__ offsP,
                                                     unsigned short* __restrict__ S) {
  int g = threadIdx.x >> 5, t = threadIdx.x & 31;
  int idx = blockIdx.x * 8 + g;
  int b = idx >> 12, p = idx & 4095;
  int h = p >> 6, w = p & 63;
  const unsigned short* actb = act1T + (size_t)b * 4096 * 256 + t * 8;
  unsigned short* Sp = S + (size_t)idx * 2304 + t * 8;
  float ov = (t < 18) ? offsP[(size_t)idx * 18 + t] : 0.f;
#pragma unroll
  for (int kk = 0; kk < 9; ++kk) {
    float offy = __shfl(ov, 2 * kk, 32);
    float offx = __shfl(ov, 2 * kk + 1, 32);
    float py = (float)(h + (kk / 3) * 2 - 2) + offy;
    float px = (float)(w + (kk % 3) * 2 - 2) + offx;
    float fy = floorf(py), fx = floorf(px);
    int y0 = (int)fy, x0 = (int)fx;
    float wy = py - fy, wx = px - fx;
    bool yv0 = (y0 >= 0 && y0 < 64), yv1 = (y0 >= -1 && y0 < 63);
    bool xv0 = (x0 >= 0 && x0 < 64), xv1 = (x0 >= -1 && x0 < 63);
    const unsigned short* cb = actb + (y0 * 64 + x0) * 256;
    uint4 q00{0,0,0,0}, q01{0,0,0,0}, q10{0,0,0,0}, q11{0,0,0,0};
    if (yv0 && xv0) q00 = *(const uint4*)(cb);
    if (yv0 && xv1) q01 = *(const uint4*)(cb + 256);
    if (yv1 && xv0) q10 = *(const uint4*)(cb + 64 * 256);
    if (yv1 && xv1) q11 = *(const uint4*)(cb + 64 * 256 + 256);
    float w00 = (1.f - wy) * (1.f - wx), w01 = (1.f - wy) * wx;
    float w10 = wy * (1.f - wx), w11 = wy * wx;
    unsigned u00[4] = {q00.x, q00.y, q00.z, q00.w};
    unsigned u01[4] = {q01.x, q01.y, q01.z, q01.w};
    unsigned u10[4] = {q10.x, q10.y, q10.z, q10.w};
    unsigned u11[4] = {q11.x, q11.y, q11.z, q11.w};
    unsigned out[4];
#pragma unroll
    for (int j = 0; j < 4; ++j) {
      float lo = bf2f((unsigned short)(u00[j] & 0xffffu)) * w00 +
                 bf2f((unsigned short)(u01[j] & 0xffffu)) * w01 +
                 bf2f((unsigned short)(u10[j] & 0xffffu)) * w10 +
                 bf2f((unsigned short)(u11[j] & 0xffffu)) * w11;
      float hi = bf2f((unsigned short)(u00[j] >> 16)) * w00 +
                 bf2f((unsigned short)(u01[j] >> 16)) * w01 +
                 bf2f((unsigned short)(u10[j] >> 16)) * w10 +
                 bf2f((unsigned short)(u11[j] >> 16)) * w11;
      out[j] = (unsigned)f2bf(lo) | ((unsigned)f2bf(hi) << 16);
    }
    *(uint4*)(Sp + kk * 256) = uint4{out[0], out[1], out[2], out[3]};
  }
}

extern "C" void kernel_launch(void* const* d_in, const int* in_sizes, int n_in,
                              void* d_out, int out_size, void* d_ws, size_t ws_size,
                              hipStream_t stream) {
  const float* x      = (const float*)d_in[0];
  const float* w1     = (const float*)d_in[1];
  const float* gamma1 = (const float*)d_in[2];
  const float* beta1  = (const float*)d_in[3];
  const float* mean1  = (const float*)d_in[4];
  const float* var1   = (const float*)d_in[5];
  const float* woff   = (const float*)d_in[6];
  const float* boff   = (const float*)d_in[7];
  const float* w2     = (const float*)d_in[8];
  const float* bconv2 = (const float*)d_in[9];
  const float* gamma2 = (const float*)d_in[10];
  const float* beta2  = (const float*)d_in[11];
  const float* mean2  = (const float*)d_in[12];
  const float* var2   = (const float*)d_in[13];
  const float* w3     = (const float*)d_in[14];
  const float* gamma3 = (const float*)d_in[15];
  const float* beta3  = (const float*)d_in[16];
  const float* mean3  = (const float*)d_in[17];
  const float* var3   = (const float*)d_in[18];

  char* ws = (char*)d_ws;
  unsigned short* xT    = (unsigned short*)(ws);                 // 33,554,432 B
  unsigned short* act1T = (unsigned short*)(ws + 33554432);      //  8,388,608
  unsigned short* act2T = (unsigned short*)(ws + 41943040);      //  8,388,608
  unsigned short* S     = (unsigned short*)(ws + 50331648);      // 75,497,472 (ends 125,829,120)
  float*          offs  = (float*)(ws + 125829120);              //  1,179,648
  unsigned short* w1b   = (unsigned short*)(ws + 127008768);     //    524,288
  unsigned short* w2r   = (unsigned short*)(ws + 127533056);     //  1,179,648
  unsigned short* w3b   = (unsigned short*)(ws + 128712704);     //    524,288
  float*          bnS1  = (float*)(ws + 129236992);              //      1,024
  float*          bnH1  = (float*)(ws + 129238016);              //      1,024
  float*          bnS2  = (float*)(ws + 129239040);              //      1,024
  float*          bnH2  = (float*)(ws + 129240064);              //      1,024
  // aliased (non-overlapping lifetimes):
  unsigned short* act1P = S;                         // 9,469,952 B at S base; dead before S written
  float*          part1 = (float*)(ws + 62914560);   // 33,554,432 B inside S region, after act1P
  float*          part2 = (float*)ws;                // 33,554,432 B in xT region (xT dead post-GEMM1)
  unsigned short* wob   = xT;                        // 147,456 B; live only reorder_woff..off_gemm
  float*          scale3 = (float*)(ws + 125829120); // 4 KB in offs region (offs dead post-sample)
  float*          shift3 = (float*)(ws + 125833216); // 4 KB

  cvt_bf16<<<1024, 256, 0, stream>>>(w1, w1b, 262144);
  reorder_w2<<<2304, 256, 0, stream>>>(w2, w2r);
  zero16<<<2312, 256, 0, stream>>>((uint4*)act1P, 591872);
  prep_bn<<<1, 256, 0, stream>>>(gamma1, beta1, mean1, var1, gamma2, beta2, mean2, var2,
                                 bconv2, bnS1, bnH1, bnS2, bnH2);
  transpose_x<<<dim3(128, 32, 4), 256, 0, stream>>>(x, xT);

  // GEMM1 (K=1024) split x2 -> fp32 partials -> BN1+ReLU epilogue (act1T + padded act1P)
  gemm_split<<<dim3(2, 128, 2), 256, 0, stream>>>(xT, w1b, part1, 16384, 256, 1024, 512);
  epi_bn<1><<<2048, 256, 0, stream>>>(part1, bnS1, bnH1, act1T, act1P);

  reorder_woff<<<288, 256, 0, stream>>>(woff, wob);
  off_gemm<<<256, 256, 0, stream>>>(act1P, wob, boff, offs);
  deform_sample<<<dim3(2048), 256, 0, stream>>>(act1T, offs, S);

  // offs now dead -> BN3 fold (scale into w3 bf16, shift kept)
  prep_bn3<<<4, 256, 0, stream>>>(gamma3, beta3, mean3, var3, scale3, shift3);
  cvt_w3s<<<1024, 256, 0, stream>>>(w3, scale3, w3b);

  // GEMM2 (K=2304) split x2 -> fp32 partials -> bias+BN2+ReLU epilogue
  gemm_split<<<dim3(2, 128, 2), 256, 0, stream>>>(S, w2r, part2, 16384, 256, 2304, 1152);
  epi_bn<0><<<2048, 256, 0, stream>>>(part2, bnS2, bnH2, act2T, nullptr);

  // GEMM3: out = relu(w3s @ act2T^T + shift3 + x)
  gemm_res<<<dim3(32, 8, 4), 256, 0, stream>>>(w3b, act2T, (float*)d_out, shift3, x,
                                               1024, 4096, 256, 4096L * 256, 4194304L);
}

// Round 6
// 308.150 us; speedup vs baseline: 1.7844x; 1.0271x over previous
//
#include <hip/hip_runtime.h>

#define EPS_BN 1e-5f

typedef __bf16 bf16x8 __attribute__((ext_vector_type(8)));
typedef float f32x4 __attribute__((ext_vector_type(4)));

__device__ __forceinline__ unsigned short f2bf(float f) {
  union { float f; unsigned u; } v; v.f = f;
  unsigned r = v.u + 0x7fffu + ((v.u >> 16) & 1u);
  return (unsigned short)(r >> 16);
}
__device__ __forceinline__ float bf2f(unsigned short h) {
  union { unsigned u; float f; } v; v.u = ((unsigned)h) << 16;
  return v.f;
}

// ---------------- fused prep: all weight conversions / reorders / BN folds / zeroing ----------------
// segA [0,1024):    w1 f32 -> bf16                    (262144)
// segB [1024,3328): w2 (256,256,3,3) -> w2r [o][kk*256+c] bf16
// segC [3328,5640): zero act1P (591872 uint4)
// segD [5640,5928): woff -> wob [32][kk*256+c] bf16 (rows 18..31 zero)
// segE [5928,6952): w3 * bn3scale -> w3b bf16
// segF [6952,6956): shift3[1024]
// segG [6956]:      bn1/bn2 folded scale+shift (256 ch)
__global__ __launch_bounds__(256) void prep_all(
    const float* __restrict__ w1, const float* __restrict__ w2, const float* __restrict__ woff,
    const float* __restrict__ w3,
    const float* g1, const float* b1, const float* m1, const float* v1,
    const float* g2, const float* b2, const float* m2, const float* v2, const float* bconv2,
    const float* g3, const float* b3, const float* m3, const float* v3,
    unsigned short* __restrict__ w1b, unsigned short* __restrict__ w2r,
    uint4* __restrict__ act1Pz, unsigned short* __restrict__ wob,
    unsigned short* __restrict__ w3b, float* __restrict__ shift3,
    float* s1, float* h1, float* s2, float* h2) {
  int bid = blockIdx.x, tid = threadIdx.x;
  if (bid < 1024) {
    int i = bid * 256 + tid;
    w1b[i] = f2bf(w1[i]);
  } else if (bid < 3328) {
    int i = (bid - 1024) * 256 + tid;
    int o = i / 2304, r = i % 2304;
    int kk = r / 256, c = r % 256;
    w2r[i] = f2bf(w2[(size_t)o * 2304 + c * 9 + kk]);
  } else if (bid < 5640) {
    int i = (bid - 3328) * 256 + tid;
    if (i < 591872) act1Pz[i] = uint4{0, 0, 0, 0};
  } else if (bid < 5928) {
    int i = (bid - 5640) * 256 + tid;
    int o = i / 2304, r = i % 2304;
    int kk = r / 256, c = r % 256;
    wob[i] = (o < 18) ? f2bf(woff[(size_t)o * 2304 + c * 9 + kk]) : (unsigned short)0;
  } else if (bid < 6952) {
    int i = (bid - 5928) * 256 + tid;
    int o = i >> 8;
    float sc = rsqrtf(v3[o] + EPS_BN) * g3[o];
    w3b[i] = f2bf(w3[i] * sc);
  } else if (bid < 6956) {
    int c = (bid - 6952) * 256 + tid;
    float sc = rsqrtf(v3[c] + EPS_BN) * g3[c];
    shift3[c] = b3[c] - m3[c] * sc;
  } else {
    int c = tid;
    float sc1 = rsqrtf(v1[c] + EPS_BN) * g1[c];
    s1[c] = sc1; h1[c] = b1[c] - m1[c] * sc1;
    float sc2 = rsqrtf(v2[c] + EPS_BN) * g2[c];
    s2[c] = sc2; h2[c] = b2[c] + (bconv2[c] - m2[c]) * sc2;
  }
}

// ---------------- x transpose: (B,1024,4096) f32 -> (B*4096, 1024) bf16 ----------------
__global__ __launch_bounds__(256) void transpose_x(const float* __restrict__ x,
                                                   unsigned short* __restrict__ xT) {
  __shared__ float t[32][33];
  int b = blockIdx.z;
  int p0 = blockIdx.x * 32, c0 = blockIdx.y * 32;
  int tx = threadIdx.x & 31, ty = threadIdx.x >> 5;
  const float* xb = x + (size_t)b * 1024 * 4096;
#pragma unroll
  for (int j = 0; j < 4; ++j) {
    int c = c0 + ty + j * 8;
    t[ty + j * 8][tx] = xb[(size_t)c * 4096 + p0 + tx];
  }
  __syncthreads();
  unsigned short* xTb = xT + (size_t)b * 4096 * 1024;
#pragma unroll
  for (int j = 0; j < 4; ++j) {
    int p = p0 + ty + j * 8;
    xTb[(size_t)p * 1024 + c0 + tx] = f2bf(t[tx][ty + j * 8]);
  }
}

// ---------------- K-split MFMA GEMM -> bf16 partials: part[z][M][256] ----------------
__global__ __launch_bounds__(256) void gemm_split(
    const unsigned short* __restrict__ A, const unsigned short* __restrict__ Bm,
    unsigned short* __restrict__ part, int M, int N, int K, int KH) {
  __shared__ unsigned short sA[128 * 32];
  __shared__ unsigned short sB[128 * 32];
  int tid = threadIdx.x, lane = tid & 63, wv = tid >> 6;
  int z = blockIdx.z;
  int m0 = blockIdx.y * 128, n0 = blockIdx.x * 128;
  f32x4 acc[4][4] = {};
  int rowA = tid >> 2;
  int kcol = (tid & 3) * 8;
  int wm = wv & 1, wn = wv >> 1;
  int lane15 = lane & 15, quad8 = (lane >> 4) * 8;
  int kend = z * KH + KH;

  for (int k0 = z * KH; k0 < kend; k0 += 32) {
    __syncthreads();
#pragma unroll
    for (int r = 0; r < 2; ++r) {
      const unsigned short* gp = A + (size_t)(m0 + r * 64 + rowA) * K + k0 + kcol;
      __builtin_amdgcn_global_load_lds((const __attribute__((address_space(1))) void*)gp,
                                       (__attribute__((address_space(3))) void*)&sA[r * 2048 + wv * 512],
                                       16, 0, 0);
    }
#pragma unroll
    for (int r = 0; r < 2; ++r) {
      const unsigned short* gp = Bm + (size_t)(n0 + r * 64 + rowA) * K + k0 + kcol;
      __builtin_amdgcn_global_load_lds((const __attribute__((address_space(1))) void*)gp,
                                       (__attribute__((address_space(3))) void*)&sB[r * 2048 + wv * 512],
                                       16, 0, 0);
    }
    __syncthreads();
    bf16x8 afr[4], bfr[4];
#pragma unroll
    for (int mi = 0; mi < 4; ++mi)
      afr[mi] = *(const bf16x8*)&sA[(wm * 64 + mi * 16 + lane15) * 32 + quad8];
#pragma unroll
    for (int ni = 0; ni < 4; ++ni)
      bfr[ni] = *(const bf16x8*)&sB[(wn * 64 + ni * 16 + lane15) * 32 + quad8];
#pragma unroll
    for (int mi = 0; mi < 4; ++mi)
#pragma unroll
      for (int ni = 0; ni < 4; ++ni)
        acc[mi][ni] = __builtin_amdgcn_mfma_f32_16x16x32_bf16(afr[mi], bfr[ni], acc[mi][ni], 0, 0, 0);
  }

  unsigned short* outH = part + (size_t)z * M * N;
#pragma unroll
  for (int mi = 0; mi < 4; ++mi) {
#pragma unroll
    for (int ni = 0; ni < 4; ++ni) {
      int col = n0 + wn * 64 + ni * 16 + lane15;
#pragma unroll
      for (int reg = 0; reg < 4; ++reg) {
        int row = m0 + wm * 64 + mi * 16 + (lane >> 4) * 4 + reg;
        outH[(size_t)row * N + col] = f2bf(acc[mi][ni][reg]);
      }
    }
  }
}

// ---------------- epilogue: sum NS bf16 partials, folded BN + ReLU -> bf16 (+opt padded copy) ----------------
template <int NS, int PAD>
__global__ __launch_bounds__(256) void epi_bn(const unsigned short* __restrict__ part,
                                              const float* __restrict__ scale,
                                              const float* __restrict__ shift,
                                              unsigned short* __restrict__ outT,
                                              unsigned short* __restrict__ outP) {
  int gid = blockIdx.x * 256 + threadIdx.x;   // 16384*32
  int row = gid >> 5, c0 = (gid & 31) * 8;
  float v[8] = {};
#pragma unroll
  for (int s = 0; s < NS; ++s) {
    uint4 q = *(const uint4*)(part + (size_t)s * 16384 * 256 + (size_t)row * 256 + c0);
    unsigned u[4] = {q.x, q.y, q.z, q.w};
#pragma unroll
    for (int j = 0; j < 4; ++j) {
      v[2 * j]     += bf2f((unsigned short)(u[j] & 0xffffu));
      v[2 * j + 1] += bf2f((unsigned short)(u[j] >> 16));
    }
  }
  float sc[8], sh[8];
  *(float4*)&sc[0] = *(const float4*)(scale + c0); *(float4*)&sc[4] = *(const float4*)(scale + c0 + 4);
  *(float4*)&sh[0] = *(const float4*)(shift + c0); *(float4*)&sh[4] = *(const float4*)(shift + c0 + 4);
  unsigned o[4];
#pragma unroll
  for (int j = 0; j < 4; ++j) {
    float lo = fmaxf(v[2 * j] * sc[2 * j] + sh[2 * j], 0.f);
    float hi = fmaxf(v[2 * j + 1] * sc[2 * j + 1] + sh[2 * j + 1], 0.f);
    o[j] = (unsigned)f2bf(lo) | ((unsigned)f2bf(hi) << 16);
  }
  uint4 pk{o[0], o[1], o[2], o[3]};
  *(uint4*)(outT + (size_t)row * 256 + c0) = pk;
  if constexpr (PAD) {
    int bb = row >> 12, p = row & 4095;
    *(uint4*)(outP + (((size_t)(bb * 68) + (p >> 6) + 2) * 68 + (p & 63) + 2) * 256 + c0) = pk;
  }
}

// ---------------- final GEMM (1x1 conv #3), BN3 pre-folded into weights ----------------
__global__ __launch_bounds__(256) void gemm_res(
    const unsigned short* __restrict__ A, const unsigned short* __restrict__ Bm,
    float* __restrict__ outp, const float* __restrict__ shift3,
    const float* __restrict__ resid, int M, int N, int K, long bStrideB, long bStrideOut) {
  __shared__ unsigned short sA[128 * 32];
  __shared__ unsigned short sB[128 * 32];
  __shared__ float tbuf[32 * 132];
  int tid = threadIdx.x, lane = tid & 63, wv = tid >> 6;
  int z = blockIdx.z;
  const unsigned short* Bz = Bm + (size_t)z * bStrideB;
  int m0 = blockIdx.y * 128, n0 = blockIdx.x * 128;
  f32x4 acc[4][4] = {};
  int rowA = tid >> 2;
  int kcol = (tid & 3) * 8;
  int wm = wv & 1, wn = wv >> 1;
  int lane15 = lane & 15, quad8 = (lane >> 4) * 8, quad = lane >> 4;

  for (int k0 = 0; k0 < K; k0 += 32) {
    __syncthreads();
#pragma unroll
    for (int r = 0; r < 2; ++r) {
      const unsigned short* gp = A + (size_t)(m0 + r * 64 + rowA) * K + k0 + kcol;
      __builtin_amdgcn_global_load_lds((const __attribute__((address_space(1))) void*)gp,
                                       (__attribute__((address_space(3))) void*)&sA[r * 2048 + wv * 512],
                                       16, 0, 0);
    }
#pragma unroll
    for (int r = 0; r < 2; ++r) {
      const unsigned short* gp = Bz + (size_t)(n0 + r * 64 + rowA) * K + k0 + kcol;
      __builtin_amdgcn_global_load_lds((const __attribute__((address_space(1))) void*)gp,
                                       (__attribute__((address_space(3))) void*)&sB[r * 2048 + wv * 512],
                                       16, 0, 0);
    }
    __syncthreads();
    bf16x8 afr[4], bfr[4];
#pragma unroll
    for (int mi = 0; mi < 4; ++mi)
      afr[mi] = *(const bf16x8*)&sA[(wm * 64 + mi * 16 + lane15) * 32 + quad8];
#pragma unroll
    for (int ni = 0; ni < 4; ++ni)
      bfr[ni] = *(const bf16x8*)&sB[(wn * 64 + ni * 16 + lane15) * 32 + quad8];
#pragma unroll
    for (int mi = 0; mi < 4; ++mi)
#pragma unroll
      for (int ni = 0; ni < 4; ++ni)
        acc[mi][ni] = __builtin_amdgcn_mfma_f32_16x16x32_bf16(afr[mi], bfr[ni], acc[mi][ni], 0, 0, 0);
  }

  float* outF = outp + (size_t)z * bStrideOut;
  const float* res = resid + (size_t)z * bStrideOut;
  int trow = tid >> 3;
  int tcol = (tid & 7) * 4;
  int growBase = m0 + (trow >> 4) * 64 + (trow & 15);
#pragma unroll
  for (int mi = 0; mi < 4; ++mi) {
    __syncthreads();
#pragma unroll
    for (int ni = 0; ni < 4; ++ni)
#pragma unroll
      for (int reg = 0; reg < 4; ++reg)
        tbuf[(wm * 16 + quad * 4 + reg) * 132 + wn * 64 + ni * 16 + lane15] = acc[mi][ni][reg];
    __syncthreads();
    int gr = growBase + mi * 16;
    float sh = shift3[gr];
    const float* rp = res + (size_t)gr * N + n0 + tcol;
    float* op = outF + (size_t)gr * N + n0 + tcol;
    const float* lp = &tbuf[trow * 132 + tcol];
#pragma unroll
    for (int j = 0; j < 4; ++j) {
      float4 rv = *(const float4*)(rp + j * 32);
      float4 lv = *(const float4*)(lp + j * 32);
      float4 ov;
      ov.x = fmaxf(lv.x + sh + rv.x, 0.f);
      ov.y = fmaxf(lv.y + sh + rv.y, 0.f);
      ov.z = fmaxf(lv.z + sh + rv.z, 0.f);
      ov.w = fmaxf(lv.w + sh + rv.w, 0.f);
      *(float4*)(op + j * 32) = ov;
    }
  }
}

// ---------------- offset conv as MFMA GEMM over padded act1P ----------------
__global__ __launch_bounds__(256) void off_gemm(const unsigned short* __restrict__ actP,
                                                const unsigned short* __restrict__ wob,
                                                const float* __restrict__ boff,
                                                float* __restrict__ offsP) {
  __shared__ unsigned short sA[64 * 64];
  __shared__ unsigned short sB[32 * 64];
  int tid = threadIdx.x, lane = tid & 63, wv = tid >> 6;
  int m0 = blockIdx.x * 64;
  int lane15 = lane & 15, quad8 = (lane >> 4) * 8;
  int rowA = tid >> 3;
  int kc = (tid & 7) * 8;

  const unsigned short* baseA[2];
#pragma unroll
  for (int r = 0; r < 2; ++r) {
    int row = m0 + r * 32 + rowA;
    int b = row >> 12, p = row & 4095;
    baseA[r] = actP + (((size_t)(b * 68) + (p >> 6) + 2) * 68 + (p & 63) + 2) * 256 + kc;
  }
  const unsigned short* baseB = wob + (size_t)rowA * 2304 + kc;

  f32x4 acc[2] = {};
  for (int kk = 0; kk < 9; ++kk) {
    int shift = ((kk / 3) * 2 - 2) * 68 + ((kk % 3) * 2 - 2);
#pragma unroll 1
    for (int c0 = 0; c0 < 256; c0 += 64) {
      __syncthreads();
#pragma unroll
      for (int r = 0; r < 2; ++r) {
        const unsigned short* gp = baseA[r] + (long)shift * 256 + c0;
        __builtin_amdgcn_global_load_lds((const __attribute__((address_space(1))) void*)gp,
                                         (__attribute__((address_space(3))) void*)&sA[r * 2048 + wv * 512],
                                         16, 0, 0);
      }
      {
        const unsigned short* gp = baseB + kk * 256 + c0;
        __builtin_amdgcn_global_load_lds((const __attribute__((address_space(1))) void*)gp,
                                         (__attribute__((address_space(3))) void*)&sB[wv * 512],
                                         16, 0, 0);
      }
      __syncthreads();
      bf16x8 afr[2], bfr[2][2];
#pragma unroll
      for (int kq = 0; kq < 2; ++kq) {
        afr[kq] = *(const bf16x8*)&sA[(wv * 16 + lane15) * 64 + kq * 32 + quad8];
#pragma unroll
        for (int ni = 0; ni < 2; ++ni)
          bfr[kq][ni] = *(const bf16x8*)&sB[(ni * 16 + lane15) * 64 + kq * 32 + quad8];
      }
#pragma unroll
      for (int kq = 0; kq < 2; ++kq)
#pragma unroll
        for (int ni = 0; ni < 2; ++ni)
          acc[ni] = __builtin_amdgcn_mfma_f32_16x16x32_bf16(afr[kq], bfr[kq][ni], acc[ni], 0, 0, 0);
    }
  }

#pragma unroll
  for (int ni = 0; ni < 2; ++ni) {
    int o = ni * 16 + lane15;
    if (o < 18) {
      float bo = boff[o];
#pragma unroll
      for (int reg = 0; reg < 4; ++reg) {
        int row = m0 + wv * 16 + (lane >> 4) * 4 + reg;
        offsP[(size_t)row * 18 + o] = acc[ni][reg] + bo;
      }
    }
  }
}

// ---------------- bilinear im2col, vectorized: 32 lanes x 8ch per pixel ----------------
__global__ __launch_bounds__(256) void deform_sample(const unsigned short* __restrict__ act1T,
                                                     const float* __restrict__ offsP,
                                                     unsigned short* __restrict__ S) {
  int g = threadIdx.x >> 5, t = threadIdx.x & 31;
  int idx = blockIdx.x * 8 + g;
  int b = idx >> 12, p = idx & 4095;
  int h = p >> 6, w = p & 63;
  const unsigned short* actb = act1T + (size_t)b * 4096 * 256 + t * 8;
  unsigned short* Sp = S + (size_t)idx * 2304 + t * 8;
  float ov = (t < 18) ? offsP[(size_t)idx * 18 + t] : 0.f;
#pragma unroll
  for (int kk = 0; kk < 9; ++kk) {
    float offy = __shfl(ov, 2 * kk, 32);
    float offx = __shfl(ov, 2 * kk + 1, 32);
    float py = (float)(h + (kk / 3) * 2 - 2) + offy;
    float px = (float)(w + (kk % 3) * 2 - 2) + offx;
    float fy = floorf(py), fx = floorf(px);
    int y0 = (int)fy, x0 = (int)fx;
    float wy = py - fy, wx = px - fx;
    bool yv0 = (y0 >= 0 && y0 < 64), yv1 = (y0 >= -1 && y0 < 63);
    bool xv0 = (x0 >= 0 && x0 < 64), xv1 = (x0 >= -1 && x0 < 63);
    const unsigned short* cb = actb + (y0 * 64 + x0) * 256;
    uint4 q00{0,0,0,0}, q01{0,0,0,0}, q10{0,0,0,0}, q11{0,0,0,0};
    if (yv0 && xv0) q00 = *(const uint4*)(cb);
    if (yv0 && xv1) q01 = *(const uint4*)(cb + 256);
    if (yv1 && xv0) q10 = *(const uint4*)(cb + 64 * 256);
    if (yv1 && xv1) q11 = *(const uint4*)(cb + 64 * 256 + 256);
    float w00 = (1.f - wy) * (1.f - wx), w01 = (1.f - wy) * wx;
    float w10 = wy * (1.f - wx), w11 = wy * wx;
    unsigned u00[4] = {q00.x, q00.y, q00.z, q00.w};
    unsigned u01[4] = {q01.x, q01.y, q01.z, q01.w};
    unsigned u10[4] = {q10.x, q10.y, q10.z, q10.w};
    unsigned u11[4] = {q11.x, q11.y, q11.z, q11.w};
    unsigned out[4];
#pragma unroll
    for (int j = 0; j < 4; ++j) {
      float lo = bf2f((unsigned short)(u00[j] & 0xffffu)) * w00 +
                 bf2f((unsigned short)(u01[j] & 0xffffu)) * w01 +
                 bf2f((unsigned short)(u10[j] & 0xffffu)) * w10 +
                 bf2f((unsigned short)(u11[j] & 0xffffu)) * w11;
      float hi = bf2f((unsigned short)(u00[j] >> 16)) * w00 +
                 bf2f((unsigned short)(u01[j] >> 16)) * w01 +
                 bf2f((unsigned short)(u10[j] >> 16)) * w10 +
                 bf2f((unsigned short)(u11[j] >> 16)) * w11;
      out[j] = (unsigned)f2bf(lo) | ((unsigned)f2bf(hi) << 16);
    }
    *(uint4*)(Sp + kk * 256) = uint4{out[0], out[1], out[2], out[3]};
  }
}

extern "C" void kernel_launch(void* const* d_in, const int* in_sizes, int n_in,
                              void* d_out, int out_size, void* d_ws, size_t ws_size,
                              hipStream_t stream) {
  const float* x      = (const float*)d_in[0];
  const float* w1     = (const float*)d_in[1];
  const float* gamma1 = (const float*)d_in[2];
  const float* beta1  = (const float*)d_in[3];
  const float* mean1  = (const float*)d_in[4];
  const float* var1   = (const float*)d_in[5];
  const float* woff   = (const float*)d_in[6];
  const float* boff   = (const float*)d_in[7];
  const float* w2     = (const float*)d_in[8];
  const float* bconv2 = (const float*)d_in[9];
  const float* gamma2 = (const float*)d_in[10];
  const float* beta2  = (const float*)d_in[11];
  const float* mean2  = (const float*)d_in[12];
  const float* var2   = (const float*)d_in[13];
  const float* w3     = (const float*)d_in[14];
  const float* gamma3 = (const float*)d_in[15];
  const float* beta3  = (const float*)d_in[16];
  const float* mean3  = (const float*)d_in[17];
  const float* var3   = (const float*)d_in[18];

  char* ws = (char*)d_ws;
  unsigned short* xT    = (unsigned short*)(ws);                 // [0, 33.55 MB)
  unsigned short* act1T = (unsigned short*)(ws + 33554432);      //  8,388,608
  unsigned short* act2T = (unsigned short*)(ws + 41943040);      //  8,388,608
  unsigned short* S     = (unsigned short*)(ws + 50331648);      // 75,497,472 (ends 125,829,120)
  float*          offs  = (float*)(ws + 125829120);              //  1,179,648
  unsigned short* w1b   = (unsigned short*)(ws + 127008768);     //    524,288
  unsigned short* w2r   = (unsigned short*)(ws + 127533056);     //  1,179,648
  unsigned short* w3b   = (unsigned short*)(ws + 128712704);     //    524,288
  float*          bnS1  = (float*)(ws + 129236992);              //      1,024
  float*          bnH1  = (float*)(ws + 129238016);              //      1,024
  float*          bnS2  = (float*)(ws + 129239040);              //      1,024
  float*          bnH2  = (float*)(ws + 129240064);              //      1,024
  float*          shift3= (float*)(ws + 129241088);              //      4,096
  // aliased (non-overlapping lifetimes):
  unsigned short* act1P = S;                                  // 9.47 MB at S base; dead before S written
  unsigned short* part1 = (unsigned short*)(ws + 62914560);   // 4x8 MB bf16, in S region after act1P
  unsigned short* part2 = (unsigned short*)ws;                // 4x8 MB bf16, xT region (dead post-GEMM1)
  unsigned short* wob   = act2T;                              // 147 KB; dead before epi_bn2 writes act2T

  prep_all<<<6957, 256, 0, stream>>>(w1, w2, woff, w3,
                                     gamma1, beta1, mean1, var1,
                                     gamma2, beta2, mean2, var2, bconv2,
                                     gamma3, beta3, mean3, var3,
                                     w1b, w2r, (uint4*)act1P, wob, w3b, shift3,
                                     bnS1, bnH1, bnS2, bnH2);
  transpose_x<<<dim3(128, 32, 4), 256, 0, stream>>>(x, xT);

  // GEMM1 (K=1024) split x4 -> bf16 partials -> BN1+ReLU epilogue (act1T + padded act1P)
  gemm_split<<<dim3(2, 128, 4), 256, 0, stream>>>(xT, w1b, part1, 16384, 256, 1024, 256);
  epi_bn<4, 1><<<2048, 256, 0, stream>>>(part1, bnS1, bnH1, act1T, act1P);

  off_gemm<<<256, 256, 0, stream>>>(act1P, wob, boff, offs);
  deform_sample<<<dim3(2048), 256, 0, stream>>>(act1T, offs, S);

  // GEMM2 (K=2304) split x4 -> bf16 partials -> bias+BN2+ReLU epilogue
  gemm_split<<<dim3(2, 128, 4), 256, 0, stream>>>(S, w2r, part2, 16384, 256, 2304, 576);
  epi_bn<4, 0><<<2048, 256, 0, stream>>>(part2, bnS2, bnH2, act2T, nullptr);

  // GEMM3: out = relu(w3s @ act2T^T + shift3 + x)
  gemm_res<<<dim3(32, 8, 4), 256, 0, stream>>>(w3b, act2T, (float*)d_out, shift3, x,
                                               1024, 4096, 256, 4096L * 256, 4194304L);
}

// Round 7
// 302.459 us; speedup vs baseline: 1.8180x; 1.0188x over previous
//
#include <hip/hip_runtime.h>

#define EPS_BN 1e-5f

typedef __bf16 bf16x8 __attribute__((ext_vector_type(8)));
typedef float f32x4 __attribute__((ext_vector_type(4)));

__device__ __forceinline__ unsigned short f2bf(float f) {
  union { float f; unsigned u; } v; v.f = f;
  unsigned r = v.u + 0x7fffu + ((v.u >> 16) & 1u);
  return (unsigned short)(r >> 16);
}
__device__ __forceinline__ float bf2f(unsigned short h) {
  union { unsigned u; float f; } v; v.u = ((unsigned)h) << 16;
  return v.f;
}

// ---------------- fused prep ----------------
__global__ __launch_bounds__(256) void prep_all(
    const float* __restrict__ w1, const float* __restrict__ w2, const float* __restrict__ woff,
    const float* __restrict__ w3,
    const float* g1, const float* b1, const float* m1, const float* v1,
    const float* g2, const float* b2, const float* m2, const float* v2, const float* bconv2,
    const float* g3, const float* b3, const float* m3, const float* v3,
    unsigned short* __restrict__ w1b, unsigned short* __restrict__ w2r,
    uint4* __restrict__ act1Pz, unsigned short* __restrict__ wob,
    unsigned short* __restrict__ w3b, float* __restrict__ shift3,
    float* s1, float* h1, float* s2, float* h2) {
  int bid = blockIdx.x, tid = threadIdx.x;
  if (bid < 1024) {
    int i = bid * 256 + tid;
    w1b[i] = f2bf(w1[i]);
  } else if (bid < 3328) {
    int i = (bid - 1024) * 256 + tid;
    int o = i / 2304, r = i % 2304;
    int kk = r / 256, c = r % 256;
    w2r[i] = f2bf(w2[(size_t)o * 2304 + c * 9 + kk]);
  } else if (bid < 5640) {
    int i = (bid - 3328) * 256 + tid;
    if (i < 591872) act1Pz[i] = uint4{0, 0, 0, 0};
  } else if (bid < 5928) {
    int i = (bid - 5640) * 256 + tid;
    int o = i / 2304, r = i % 2304;
    int kk = r / 256, c = r % 256;
    wob[i] = (o < 18) ? f2bf(woff[(size_t)o * 2304 + c * 9 + kk]) : (unsigned short)0;
  } else if (bid < 6952) {
    int i = (bid - 5928) * 256 + tid;
    int o = i >> 8;
    float sc = rsqrtf(v3[o] + EPS_BN) * g3[o];
    w3b[i] = f2bf(w3[i] * sc);
  } else if (bid < 6956) {
    int c = (bid - 6952) * 256 + tid;
    float sc = rsqrtf(v3[c] + EPS_BN) * g3[c];
    shift3[c] = b3[c] - m3[c] * sc;
  } else {
    int c = tid;
    float sc1 = rsqrtf(v1[c] + EPS_BN) * g1[c];
    s1[c] = sc1; h1[c] = b1[c] - m1[c] * sc1;
    float sc2 = rsqrtf(v2[c] + EPS_BN) * g2[c];
    s2[c] = sc2; h2[c] = b2[c] + (bconv2[c] - m2[c]) * sc2;
  }
}

// ---------------- x transpose: (B,1024,4096) f32 -> (B*4096, 1024) bf16, packed stores ----------------
__global__ __launch_bounds__(256) void transpose_x(const float* __restrict__ x,
                                                   unsigned short* __restrict__ xT) {
  __shared__ float t[32][33];
  int b = blockIdx.z;
  int p0 = blockIdx.x * 32, c0 = blockIdx.y * 32;
  int tx = threadIdx.x & 31, ty = threadIdx.x >> 5;
  const float* xb = x + (size_t)b * 1024 * 4096;
#pragma unroll
  for (int j = 0; j < 4; ++j) {
    int c = c0 + ty + j * 8;
    t[ty + j * 8][tx] = xb[(size_t)c * 4096 + p0 + tx];
  }
  __syncthreads();
  unsigned short* xTb = xT + (size_t)b * 4096 * 1024;
  int pl = threadIdx.x >> 3;        // 0..31
  int cl = (threadIdx.x & 7) * 4;   // 0..28
  float v0 = t[cl][pl], v1 = t[cl + 1][pl], v2 = t[cl + 2][pl], v3 = t[cl + 3][pl];
  uint2 pk;
  pk.x = (unsigned)f2bf(v0) | ((unsigned)f2bf(v1) << 16);
  pk.y = (unsigned)f2bf(v2) | ((unsigned)f2bf(v3) << 16);
  *(uint2*)(xTb + (size_t)(p0 + pl) * 1024 + c0 + cl) = pk;
}

// ---------------- K-split MFMA GEMM -> bf16 partials, vectorized epilogue ----------------
__global__ __launch_bounds__(256) void gemm_split(
    const unsigned short* __restrict__ A, const unsigned short* __restrict__ Bm,
    unsigned short* __restrict__ part, int M, int N, int K, int KH) {
  __shared__ unsigned short sA[128 * 32];
  __shared__ unsigned short sB[128 * 32];
  __shared__ float tbuf[32 * 132];
  int tid = threadIdx.x, lane = tid & 63, wv = tid >> 6;
  int z = blockIdx.z;
  int m0 = blockIdx.y * 128, n0 = blockIdx.x * 128;
  f32x4 acc[4][4] = {};
  int rowA = tid >> 2;
  int kcol = (tid & 3) * 8;
  int wm = wv & 1, wn = wv >> 1;
  int lane15 = lane & 15, quad8 = (lane >> 4) * 8, quad = lane >> 4;
  int kend = z * KH + KH;

  for (int k0 = z * KH; k0 < kend; k0 += 32) {
    __syncthreads();
#pragma unroll
    for (int r = 0; r < 2; ++r) {
      const unsigned short* gp = A + (size_t)(m0 + r * 64 + rowA) * K + k0 + kcol;
      __builtin_amdgcn_global_load_lds((const __attribute__((address_space(1))) void*)gp,
                                       (__attribute__((address_space(3))) void*)&sA[r * 2048 + wv * 512],
                                       16, 0, 0);
    }
#pragma unroll
    for (int r = 0; r < 2; ++r) {
      const unsigned short* gp = Bm + (size_t)(n0 + r * 64 + rowA) * K + k0 + kcol;
      __builtin_amdgcn_global_load_lds((const __attribute__((address_space(1))) void*)gp,
                                       (__attribute__((address_space(3))) void*)&sB[r * 2048 + wv * 512],
                                       16, 0, 0);
    }
    __syncthreads();
    bf16x8 afr[4], bfr[4];
#pragma unroll
    for (int mi = 0; mi < 4; ++mi)
      afr[mi] = *(const bf16x8*)&sA[(wm * 64 + mi * 16 + lane15) * 32 + quad8];
#pragma unroll
    for (int ni = 0; ni < 4; ++ni)
      bfr[ni] = *(const bf16x8*)&sB[(wn * 64 + ni * 16 + lane15) * 32 + quad8];
#pragma unroll
    for (int mi = 0; mi < 4; ++mi)
#pragma unroll
      for (int ni = 0; ni < 4; ++ni)
        acc[mi][ni] = __builtin_amdgcn_mfma_f32_16x16x32_bf16(afr[mi], bfr[ni], acc[mi][ni], 0, 0, 0);
  }

  // vectorized epilogue: LDS-transpose each 32-row chunk, pack 16ch/thread -> 2 uint4 stores
  unsigned short* outH = part + (size_t)z * M * N;
  int trow = tid >> 3;              // 0..31
  int tcol16 = (tid & 7) * 16;      // 0..112
  int growBase = m0 + (trow >> 4) * 64 + (trow & 15);
#pragma unroll
  for (int mi = 0; mi < 4; ++mi) {
    __syncthreads();
#pragma unroll
    for (int ni = 0; ni < 4; ++ni)
#pragma unroll
      for (int reg = 0; reg < 4; ++reg)
        tbuf[(wm * 16 + quad * 4 + reg) * 132 + wn * 64 + ni * 16 + lane15] = acc[mi][ni][reg];
    __syncthreads();
    int gr = growBase + mi * 16;
    const float* lp = &tbuf[trow * 132 + tcol16];
    unsigned o[8];
#pragma unroll
    for (int j = 0; j < 8; ++j)
      o[j] = (unsigned)f2bf(lp[2 * j]) | ((unsigned)f2bf(lp[2 * j + 1]) << 16);
    unsigned short* op = outH + (size_t)gr * 256 + n0 + tcol16;
    *(uint4*)(op) = uint4{o[0], o[1], o[2], o[3]};
    *(uint4*)(op + 8) = uint4{o[4], o[5], o[6], o[7]};
  }
}

// ---------------- epilogue: sum NS bf16 partials, folded BN + ReLU -> bf16 (+opt padded copy) ----------------
template <int NS, int PAD>
__global__ __launch_bounds__(256) void epi_bn(const unsigned short* __restrict__ part,
                                              const float* __restrict__ scale,
                                              const float* __restrict__ shift,
                                              unsigned short* __restrict__ outT,
                                              unsigned short* __restrict__ outP) {
  int gid = blockIdx.x * 256 + threadIdx.x;   // 16384*32
  int row = gid >> 5, c0 = (gid & 31) * 8;
  float v[8] = {};
#pragma unroll
  for (int s = 0; s < NS; ++s) {
    uint4 q = *(const uint4*)(part + (size_t)s * 16384 * 256 + (size_t)row * 256 + c0);
    unsigned u[4] = {q.x, q.y, q.z, q.w};
#pragma unroll
    for (int j = 0; j < 4; ++j) {
      v[2 * j]     += bf2f((unsigned short)(u[j] & 0xffffu));
      v[2 * j + 1] += bf2f((unsigned short)(u[j] >> 16));
    }
  }
  float sc[8], sh[8];
  *(float4*)&sc[0] = *(const float4*)(scale + c0); *(float4*)&sc[4] = *(const float4*)(scale + c0 + 4);
  *(float4*)&sh[0] = *(const float4*)(shift + c0); *(float4*)&sh[4] = *(const float4*)(shift + c0 + 4);
  unsigned o[4];
#pragma unroll
  for (int j = 0; j < 4; ++j) {
    float lo = fmaxf(v[2 * j] * sc[2 * j] + sh[2 * j], 0.f);
    float hi = fmaxf(v[2 * j + 1] * sc[2 * j + 1] + sh[2 * j + 1], 0.f);
    o[j] = (unsigned)f2bf(lo) | ((unsigned)f2bf(hi) << 16);
  }
  uint4 pk{o[0], o[1], o[2], o[3]};
  *(uint4*)(outT + (size_t)row * 256 + c0) = pk;
  if constexpr (PAD) {
    int bb = row >> 12, p = row & 4095;
    *(uint4*)(outP + (((size_t)(bb * 68) + (p >> 6) + 2) * 68 + (p & 63) + 2) * 256 + c0) = pk;
  }
}

// ---------------- final GEMM (1x1 conv #3), BN3 pre-folded into weights ----------------
__global__ __launch_bounds__(256) void gemm_res(
    const unsigned short* __restrict__ A, const unsigned short* __restrict__ Bm,
    float* __restrict__ outp, const float* __restrict__ shift3,
    const float* __restrict__ resid, int M, int N, int K, long bStrideB, long bStrideOut) {
  __shared__ unsigned short sA[128 * 32];
  __shared__ unsigned short sB[128 * 32];
  __shared__ float tbuf[32 * 132];
  int tid = threadIdx.x, lane = tid & 63, wv = tid >> 6;
  int z = blockIdx.z;
  const unsigned short* Bz = Bm + (size_t)z * bStrideB;
  int m0 = blockIdx.y * 128, n0 = blockIdx.x * 128;
  f32x4 acc[4][4] = {};
  int rowA = tid >> 2;
  int kcol = (tid & 3) * 8;
  int wm = wv & 1, wn = wv >> 1;
  int lane15 = lane & 15, quad8 = (lane >> 4) * 8, quad = lane >> 4;

  for (int k0 = 0; k0 < K; k0 += 32) {
    __syncthreads();
#pragma unroll
    for (int r = 0; r < 2; ++r) {
      const unsigned short* gp = A + (size_t)(m0 + r * 64 + rowA) * K + k0 + kcol;
      __builtin_amdgcn_global_load_lds((const __attribute__((address_space(1))) void*)gp,
                                       (__attribute__((address_space(3))) void*)&sA[r * 2048 + wv * 512],
                                       16, 0, 0);
    }
#pragma unroll
    for (int r = 0; r < 2; ++r) {
      const unsigned short* gp = Bz + (size_t)(n0 + r * 64 + rowA) * K + k0 + kcol;
      __builtin_amdgcn_global_load_lds((const __attribute__((address_space(1))) void*)gp,
                                       (__attribute__((address_space(3))) void*)&sB[r * 2048 + wv * 512],
                                       16, 0, 0);
    }
    __syncthreads();
    bf16x8 afr[4], bfr[4];
#pragma unroll
    for (int mi = 0; mi < 4; ++mi)
      afr[mi] = *(const bf16x8*)&sA[(wm * 64 + mi * 16 + lane15) * 32 + quad8];
#pragma unroll
    for (int ni = 0; ni < 4; ++ni)
      bfr[ni] = *(const bf16x8*)&sB[(wn * 64 + ni * 16 + lane15) * 32 + quad8];
#pragma unroll
    for (int mi = 0; mi < 4; ++mi)
#pragma unroll
      for (int ni = 0; ni < 4; ++ni)
        acc[mi][ni] = __builtin_amdgcn_mfma_f32_16x16x32_bf16(afr[mi], bfr[ni], acc[mi][ni], 0, 0, 0);
  }

  float* outF = outp + (size_t)z * bStrideOut;
  const float* res = resid + (size_t)z * bStrideOut;
  int trow = tid >> 3;
  int tcol = (tid & 7) * 4;
  int growBase = m0 + (trow >> 4) * 64 + (trow & 15);
#pragma unroll
  for (int mi = 0; mi < 4; ++mi) {
    __syncthreads();
#pragma unroll
    for (int ni = 0; ni < 4; ++ni)
#pragma unroll
      for (int reg = 0; reg < 4; ++reg)
        tbuf[(wm * 16 + quad * 4 + reg) * 132 + wn * 64 + ni * 16 + lane15] = acc[mi][ni][reg];
    __syncthreads();
    int gr = growBase + mi * 16;
    float sh = shift3[gr];
    const float* rp = res + (size_t)gr * N + n0 + tcol;
    float* op = outF + (size_t)gr * N + n0 + tcol;
    const float* lp = &tbuf[trow * 132 + tcol];
#pragma unroll
    for (int j = 0; j < 4; ++j) {
      float4 rv = *(const float4*)(rp + j * 32);
      float4 lv = *(const float4*)(lp + j * 32);
      float4 ov;
      ov.x = fmaxf(lv.x + sh + rv.x, 0.f);
      ov.y = fmaxf(lv.y + sh + rv.y, 0.f);
      ov.z = fmaxf(lv.z + sh + rv.z, 0.f);
      ov.w = fmaxf(lv.w + sh + rv.w, 0.f);
      *(float4*)(op + j * 32) = ov;
    }
  }
}

// ---------------- offset conv as MFMA GEMM over padded act1P ----------------
__global__ __launch_bounds__(256) void off_gemm(const unsigned short* __restrict__ actP,
                                                const unsigned short* __restrict__ wob,
                                                const float* __restrict__ boff,
                                                float* __restrict__ offsP) {
  __shared__ unsigned short sA[64 * 64];
  __shared__ unsigned short sB[32 * 64];
  int tid = threadIdx.x, lane = tid & 63, wv = tid >> 6;
  int m0 = blockIdx.x * 64;
  int lane15 = lane & 15, quad8 = (lane >> 4) * 8;
  int rowA = tid >> 3;
  int kc = (tid & 7) * 8;

  const unsigned short* baseA[2];
#pragma unroll
  for (int r = 0; r < 2; ++r) {
    int row = m0 + r * 32 + rowA;
    int b = row >> 12, p = row & 4095;
    baseA[r] = actP + (((size_t)(b * 68) + (p >> 6) + 2) * 68 + (p & 63) + 2) * 256 + kc;
  }
  const unsigned short* baseB = wob + (size_t)rowA * 2304 + kc;

  f32x4 acc[2] = {};
  for (int kk = 0; kk < 9; ++kk) {
    int shift = ((kk / 3) * 2 - 2) * 68 + ((kk % 3) * 2 - 2);
#pragma unroll 1
    for (int c0 = 0; c0 < 256; c0 += 64) {
      __syncthreads();
#pragma unroll
      for (int r = 0; r < 2; ++r) {
        const unsigned short* gp = baseA[r] + (long)shift * 256 + c0;
        __builtin_amdgcn_global_load_lds((const __attribute__((address_space(1))) void*)gp,
                                         (__attribute__((address_space(3))) void*)&sA[r * 2048 + wv * 512],
                                         16, 0, 0);
      }
      {
        const unsigned short* gp = baseB + kk * 256 + c0;
        __builtin_amdgcn_global_load_lds((const __attribute__((address_space(1))) void*)gp,
                                         (__attribute__((address_space(3))) void*)&sB[wv * 512],
                                         16, 0, 0);
      }
      __syncthreads();
      bf16x8 afr[2], bfr[2][2];
#pragma unroll
      for (int kq = 0; kq < 2; ++kq) {
        afr[kq] = *(const bf16x8*)&sA[(wv * 16 + lane15) * 64 + kq * 32 + quad8];
#pragma unroll
        for (int ni = 0; ni < 2; ++ni)
          bfr[kq][ni] = *(const bf16x8*)&sB[(ni * 16 + lane15) * 64 + kq * 32 + quad8];
      }
#pragma unroll
      for (int kq = 0; kq < 2; ++kq)
#pragma unroll
        for (int ni = 0; ni < 2; ++ni)
          acc[ni] = __builtin_amdgcn_mfma_f32_16x16x32_bf16(afr[kq], bfr[kq][ni], acc[ni], 0, 0, 0);
    }
  }

#pragma unroll
  for (int ni = 0; ni < 2; ++ni) {
    int o = ni * 16 + lane15;
    if (o < 18) {
      float bo = boff[o];
#pragma unroll
      for (int reg = 0; reg < 4; ++reg) {
        int row = m0 + wv * 16 + (lane >> 4) * 4 + reg;
        offsP[(size_t)row * 18 + o] = acc[ni][reg] + bo;
      }
    }
  }
}

// ---------------- bilinear im2col, vectorized: 32 lanes x 8ch per pixel ----------------
__global__ __launch_bounds__(256) void deform_sample(const unsigned short* __restrict__ act1T,
                                                     const float* __restrict__ offsP,
                                                     unsigned short* __restrict__ S) {
  int g = threadIdx.x >> 5, t = threadIdx.x & 31;
  int idx = blockIdx.x * 8 + g;
  int b = idx >> 12, p = idx & 4095;
  int h = p >> 6, w = p & 63;
  const unsigned short* actb = act1T + (size_t)b * 4096 * 256 + t * 8;
  unsigned short* Sp = S + (size_t)idx * 2304 + t * 8;
  float ov = (t < 18) ? offsP[(size_t)idx * 18 + t] : 0.f;
#pragma unroll
  for (int kk = 0; kk < 9; ++kk) {
    float offy = __shfl(ov, 2 * kk, 32);
    float offx = __shfl(ov, 2 * kk + 1, 32);
    float py = (float)(h + (kk / 3) * 2 - 2) + offy;
    float px = (float)(w + (kk % 3) * 2 - 2) + offx;
    float fy = floorf(py), fx = floorf(px);
    int y0 = (int)fy, x0 = (int)fx;
    float wy = py - fy, wx = px - fx;
    bool yv0 = (y0 >= 0 && y0 < 64), yv1 = (y0 >= -1 && y0 < 63);
    bool xv0 = (x0 >= 0 && x0 < 64), xv1 = (x0 >= -1 && x0 < 63);
    const unsigned short* cb = actb + (y0 * 64 + x0) * 256;
    uint4 q00{0,0,0,0}, q01{0,0,0,0}, q10{0,0,0,0}, q11{0,0,0,0};
    if (yv0 && xv0) q00 = *(const uint4*)(cb);
    if (yv0 && xv1) q01 = *(const uint4*)(cb + 256);
    if (yv1 && xv0) q10 = *(const uint4*)(cb + 64 * 256);
    if (yv1 && xv1) q11 = *(const uint4*)(cb + 64 * 256 + 256);
    float w00 = (1.f - wy) * (1.f - wx), w01 = (1.f - wy) * wx;
    float w10 = wy * (1.f - wx), w11 = wy * wx;
    unsigned u00[4] = {q00.x, q00.y, q00.z, q00.w};
    unsigned u01[4] = {q01.x, q01.y, q01.z, q01.w};
    unsigned u10[4] = {q10.x, q10.y, q10.z, q10.w};
    unsigned u11[4] = {q11.x, q11.y, q11.z, q11.w};
    unsigned out[4];
#pragma unroll
    for (int j = 0; j < 4; ++j) {
      float lo = bf2f((unsigned short)(u00[j] & 0xffffu)) * w00 +
                 bf2f((unsigned short)(u01[j] & 0xffffu)) * w01 +
                 bf2f((unsigned short)(u10[j] & 0xffffu)) * w10 +
                 bf2f((unsigned short)(u11[j] & 0xffffu)) * w11;
      float hi = bf2f((unsigned short)(u00[j] >> 16)) * w00 +
                 bf2f((unsigned short)(u01[j] >> 16)) * w01 +
                 bf2f((unsigned short)(u10[j] >> 16)) * w10 +
                 bf2f((unsigned short)(u11[j] >> 16)) * w11;
      out[j] = (unsigned)f2bf(lo) | ((unsigned)f2bf(hi) << 16);
    }
    *(uint4*)(Sp + kk * 256) = uint4{out[0], out[1], out[2], out[3]};
  }
}

extern "C" void kernel_launch(void* const* d_in, const int* in_sizes, int n_in,
                              void* d_out, int out_size, void* d_ws, size_t ws_size,
                              hipStream_t stream) {
  const float* x      = (const float*)d_in[0];
  const float* w1     = (const float*)d_in[1];
  const float* gamma1 = (const float*)d_in[2];
  const float* beta1  = (const float*)d_in[3];
  const float* mean1  = (const float*)d_in[4];
  const float* var1   = (const float*)d_in[5];
  const float* woff   = (const float*)d_in[6];
  const float* boff   = (const float*)d_in[7];
  const float* w2     = (const float*)d_in[8];
  const float* bconv2 = (const float*)d_in[9];
  const float* gamma2 = (const float*)d_in[10];
  const float* beta2  = (const float*)d_in[11];
  const float* mean2  = (const float*)d_in[12];
  const float* var2   = (const float*)d_in[13];
  const float* w3     = (const float*)d_in[14];
  const float* gamma3 = (const float*)d_in[15];
  const float* beta3  = (const float*)d_in[16];
  const float* mean3  = (const float*)d_in[17];
  const float* var3   = (const float*)d_in[18];

  char* ws = (char*)d_ws;
  unsigned short* xT    = (unsigned short*)(ws);                 // [0, 33.55 MB)
  unsigned short* act1T = (unsigned short*)(ws + 33554432);      //  8,388,608
  unsigned short* act2T = (unsigned short*)(ws + 41943040);      //  8,388,608
  unsigned short* S     = (unsigned short*)(ws + 50331648);      // 75,497,472 (ends 125,829,120)
  float*          offs  = (float*)(ws + 125829120);              //  1,179,648
  unsigned short* w1b   = (unsigned short*)(ws + 127008768);     //    524,288
  unsigned short* w2r   = (unsigned short*)(ws + 127533056);     //  1,179,648
  unsigned short* w3b   = (unsigned short*)(ws + 128712704);     //    524,288
  float*          bnS1  = (float*)(ws + 129236992);              //      1,024
  float*          bnH1  = (float*)(ws + 129238016);              //      1,024
  float*          bnS2  = (float*)(ws + 129239040);              //      1,024
  float*          bnH2  = (float*)(ws + 129240064);              //      1,024
  float*          shift3= (float*)(ws + 129241088);              //      4,096
  // aliased (non-overlapping lifetimes):
  unsigned short* act1P = S;                                  // 9.47 MB at S base; dead before S written
  unsigned short* part1 = (unsigned short*)(ws + 62914560);   // 2x8 MB bf16, in S region after act1P
  unsigned short* part2 = (unsigned short*)ws;                // 2x8 MB bf16, xT region (dead post-GEMM1)
  unsigned short* wob   = act2T;                              // 147 KB; dead before epi_bn2 writes act2T

  prep_all<<<6957, 256, 0, stream>>>(w1, w2, woff, w3,
                                     gamma1, beta1, mean1, var1,
                                     gamma2, beta2, mean2, var2, bconv2,
                                     gamma3, beta3, mean3, var3,
                                     w1b, w2r, (uint4*)act1P, wob, w3b, shift3,
                                     bnS1, bnH1, bnS2, bnH2);
  transpose_x<<<dim3(128, 32, 4), 256, 0, stream>>>(x, xT);

  // GEMM1 (K=1024) split x2 -> bf16 partials -> BN1+ReLU epilogue (act1T + padded act1P)
  gemm_split<<<dim3(2, 128, 2), 256, 0, stream>>>(xT, w1b, part1, 16384, 256, 1024, 512);
  epi_bn<2, 1><<<2048, 256, 0, stream>>>(part1, bnS1, bnH1, act1T, act1P);

  off_gemm<<<256, 256, 0, stream>>>(act1P, wob, boff, offs);
  deform_sample<<<dim3(2048), 256, 0, stream>>>(act1T, offs, S);

  // GEMM2 (K=2304) split x2 -> bf16 partials -> bias+BN2+ReLU epilogue
  gemm_split<<<dim3(2, 128, 2), 256, 0, stream>>>(S, w2r, part2, 16384, 256, 2304, 1152);
  epi_bn<2, 0><<<2048, 256, 0, stream>>>(part2, bnS2, bnH2, act2T, nullptr);

  // GEMM3: out = relu(w3s @ act2T^T + shift3 + x)
  gemm_res<<<dim3(32, 8, 4), 256, 0, stream>>>(w3b, act2T, (float*)d_out, shift3, x,
                                               1024, 4096, 256, 4096L * 256, 4194304L);
}